// Round 6
// baseline (743.088 us; speedup 1.0000x reference)
//
#include <hip/hip_runtime.h>
#include <hip/hip_bf16.h>
#include <hip/hip_fp16.h>

typedef __hip_bfloat16 bf16_t;

#define NU 100000
#define NI 100000
#define NB_ 5000
#define NC_ 2000
#define NR_ 50000
#define NE 600000
#define NEB 100000
#define NEC 200000
#define NER 400000
#define NPERM (2 * NE + NEB + NEC + NER)   // 1,900,000
#define NRELE (NEB + NEC + NER)            // 700,000
#define NALL (NE + NRELE)
#define SCAN_N (2 * NU + NI + 1)
#define SCAN_CHUNK 2048
#define SCAN_NCHUNK ((SCAN_N + SCAN_CHUNK - 1) / SCAN_CHUNK)   // 147

typedef __attribute__((ext_vector_type(8))) short short8;
typedef __attribute__((ext_vector_type(4))) short short4v;
typedef __attribute__((ext_vector_type(4))) float f32x4;

__device__ __forceinline__ float b2f(bf16_t x) { return __bfloat162float(x); }
__device__ __forceinline__ float sane(float x) { return isfinite(x) ? x : 0.f; }
__device__ __forceinline__ unsigned short f2bu(float x) {
    union { bf16_t b; unsigned short u; } c; c.b = __float2bfloat16(x); return c.u;
}

// dual-dtype load/store: external float tensors are f32 or bf16, per runtime flag
__device__ __forceinline__ float ldf(const void* p, size_t i, int f32) {
    return f32 ? ((const float*)p)[i] : __bfloat162float(((const bf16_t*)p)[i]);
}
__device__ __forceinline__ void stf(void* p, size_t i, float v, int f32) {
    if (f32) ((float*)p)[i] = v;
    else     ((bf16_t*)p)[i] = __float2bfloat16(v);
}

// 4-wide packed loads (i must be a multiple of 4 elements)
__device__ __forceinline__ f32x4 bf4(const bf16_t* p) {
    short4v s = *(const short4v*)p;
    f32x4 r;
#pragma unroll
    for (int q = 0; q < 4; ++q)
        r[q] = __uint_as_float(((unsigned)(unsigned short)s[q]) << 16);
    return r;
}
__device__ __forceinline__ f32x4 ldf4(const void* p, size_t i, int f32) {
    if (f32) return *(const f32x4*)((const float*)p + i);
    return bf4((const bf16_t*)p + i);
}

// ---- dtype probe: basis_freq[0] == 1.0f exactly; f32 word = 0x3F800000 ----
__global__ void detect_dtype(const unsigned int* w, int* flag) {
    if (threadIdx.x == 0 && blockIdx.x == 0) *flag = (w[0] == 0x3F800000u) ? 1 : 0;
}

// ---- wcomb_r = W_feat_r @ Wr_r (bf16 out, internal) ----
__global__ void combine_w(const void* Wb, const void* Wr0,
                          const void* Wc, const void* Wr1,
                          const void* Wr, const void* Wr2,
                          bf16_t* out, const int* flagp) {
    int f = *flagp;
    const void* A = blockIdx.x == 0 ? Wb : (blockIdx.x == 1 ? Wc : Wr);
    const void* B = blockIdx.x == 0 ? Wr0 : (blockIdx.x == 1 ? Wr1 : Wr2);
    bf16_t* O = out + (size_t)blockIdx.x * 4096;
    for (int idx = threadIdx.x; idx < 4096; idx += blockDim.x) {
        int i = idx >> 6, j = idx & 63;
        float acc = 0.f;
        for (int k = 0; k < 64; ++k)
            acc = fmaf(ldf(A, i * 64 + k, f), ldf(B, k * 64 + j, f), acc);
        O[idx] = __float2bfloat16(acc);
    }
}

// ============================================================================
// Segmented multi-tile MFMA GEMM: up to 3 segments, each out=act(A@W[+bias]).
// Grid-strides over 64-row tiles; W staged in LDS once per segment per block
// (tile sequence is block-uniform -> barriers are safe).
// ============================================================================
struct GSeg {
    const void* A; const void* W; void* out;
    const void* hext; const bf16_t* relb;
    int M; int orow0; int out_mode; int a_internal; int w_internal;
};

__global__ __launch_bounds__(256) void gemm_multi(
    GSeg s0, GSeg s1, GSeg s2, int nseg, int K, const int* __restrict__ flagp) {
    __shared__ short WL[128 * 64];   // 16 KB max (K*64 used)
    int f = *flagp;
    int nt0 = (s0.M + 63) >> 6;
    int nt1 = (nseg > 1) ? ((s1.M + 63) >> 6) : 0;
    int nt2 = (nseg > 2) ? ((s2.M + 63) >> 6) : 0;
    int ntT = nt0 + nt1 + nt2;
    int lane = threadIdx.x & 63;
    int wv = threadIdx.x >> 6;
    int q = lane >> 4, nl = lane & 15;
    int KK = K >> 5;
    int staged = -1;
    for (int tile = blockIdx.x; tile < ntT; tile += gridDim.x) {
        int sidx, t_in;
        if (tile < nt0) { sidx = 0; t_in = tile; }
        else if (tile < nt0 + nt1) { sidx = 1; t_in = tile - nt0; }
        else { sidx = 2; t_in = tile - nt0 - nt1; }
        const void* A; const void* W; void* out; const void* hext; const bf16_t* relb;
        int M, orow0, out_mode, a_int, w_int;
        if (sidx == 0) {
            A = s0.A; W = s0.W; out = s0.out; hext = s0.hext; relb = s0.relb;
            M = s0.M; orow0 = s0.orow0; out_mode = s0.out_mode; a_int = s0.a_internal; w_int = s0.w_internal;
        } else if (sidx == 1) {
            A = s1.A; W = s1.W; out = s1.out; hext = s1.hext; relb = s1.relb;
            M = s1.M; orow0 = s1.orow0; out_mode = s1.out_mode; a_int = s1.a_internal; w_int = s1.w_internal;
        } else {
            A = s2.A; W = s2.W; out = s2.out; hext = s2.hext; relb = s2.relb;
            M = s2.M; orow0 = s2.orow0; out_mode = s2.out_mode; a_int = s2.a_internal; w_int = s2.w_internal;
        }
        if (sidx != staged) {                       // block-uniform condition
            __syncthreads();                        // drain readers of old WL
            int w_f32 = w_int ? 0 : f;
            for (int i = threadIdx.x; i < K * 64; i += 256) {
                int j = i & 7, ln = (i >> 3) & 63, p = i >> 9;
                int kk4 = p >> 2, n0t = p & 3;
                int srow = kk4 * 32 + (ln >> 4) * 8 + j;
                int scol = n0t * 16 + (ln & 15);
                float wvv = w_f32 ? ((const float*)W)[srow * 64 + scol]
                                  : b2f(((const bf16_t*)W)[srow * 64 + scol]);
                WL[i] = (short)f2bu(wvv);
            }
            __syncthreads();
            staged = sidx;
        }
        int m0 = t_in * 64 + wv * 16;
        if (m0 < M) {
            int a_f32 = a_int ? 0 : f;
            int arow = m0 + nl; if (arow >= M) arow = M - 1;
            f32x4 acc[4];
#pragma unroll
            for (int t = 0; t < 4; ++t) acc[t] = (f32x4){0.f, 0.f, 0.f, 0.f};
            for (int kk4 = 0; kk4 < KK; ++kk4) {
                short8 af;
                size_t abase = (size_t)arow * K + kk4 * 32 + q * 8;
                if (a_f32) {
                    const f32x4* ap = (const f32x4*)((const float*)A + abase);
                    f32x4 x0 = ap[0], x1 = ap[1];
#pragma unroll
                    for (int j = 0; j < 4; ++j) {
                        af[j] = (short)f2bu(x0[j]);
                        af[4 + j] = (short)f2bu(x1[j]);
                    }
                } else {
                    af = *(const short8*)((const bf16_t*)A + abase);
                }
#pragma unroll
                for (int n0t = 0; n0t < 4; ++n0t) {
                    short8 bfr = *(const short8*)&WL[(((kk4 << 2) + n0t) * 64 + lane) * 8];
                    acc[n0t] = __builtin_amdgcn_mfma_f32_16x16x32_bf16(af, bfr, acc[n0t], 0, 0, 0);
                }
            }
#pragma unroll
            for (int n0t = 0; n0t < 4; ++n0t) {
#pragma unroll
                for (int r = 0; r < 4; ++r) {
                    int row = m0 + q * 4 + r;
                    if (row >= M) continue;
                    int col = n0t * 16 + nl;
                    float v = acc[n0t][r];
                    if (out_mode == 1) {
                        v += ldf(hext, (size_t)row * 64 + col, f);
                        if (relb) v += b2f(relb[(size_t)row * 64 + col]);
                        v = v > 0.f ? v : expm1f(v);
                        stf(out, (size_t)(row + orow0) * 64 + col, sane(v), f);
                    } else {
                        ((bf16_t*)out)[(size_t)row * 64 + col] = __float2bfloat16(v);
                    }
                }
            }
        }
    }
}

// ---- one-launch degree histogram over all edge sets ----
__global__ __launch_bounds__(256) void hist_all(
    const int* __restrict__ e_uid, const int* __restrict__ e_iid,
    const int* __restrict__ eb_dst, const int* __restrict__ ec_dst,
    const int* __restrict__ er_dst, int* __restrict__ deg) {
    int t = blockIdx.x * blockDim.x + threadIdx.x;
    if (t < NE) {
        atomicAdd(deg + e_uid[t], 1);
        atomicAdd(deg + NU + e_iid[t], 1);
    } else if (t < NE + NEB) {
        atomicAdd(deg + 2 * NU + eb_dst[t - NE], 1);
    } else if (t < NE + NEB + NEC) {
        atomicAdd(deg + 2 * NU + ec_dst[t - NE - NEB], 1);
    } else if (t < NALL) {
        atomicAdd(deg + 2 * NU + er_dst[t - NE - NEB - NEC], 1);
    }
}

// ---- exclusive scan over SCAN_N ints ----
__global__ __launch_bounds__(256) void scan1(const int* __restrict__ deg,
                                             int* __restrict__ off,
                                             int* __restrict__ ctot) {
    __shared__ int part[256];
    int base = blockIdx.x * SCAN_CHUNK + threadIdx.x * 8;
    int v[8]; int s = 0;
#pragma unroll
    for (int k = 0; k < 8; ++k) {
        int idx = base + k;
        v[k] = s;
        s += (idx < SCAN_N) ? deg[idx] : 0;
    }
    part[threadIdx.x] = s;
    __syncthreads();
    for (int o = 1; o < 256; o <<= 1) {
        int t = (threadIdx.x >= o) ? part[threadIdx.x - o] : 0;
        __syncthreads();
        part[threadIdx.x] += t;
        __syncthreads();
    }
    int texc = (threadIdx.x == 0) ? 0 : part[threadIdx.x - 1];
#pragma unroll
    for (int k = 0; k < 8; ++k) {
        int idx = base + k;
        if (idx < SCAN_N) off[idx] = texc + v[k];
    }
    if (threadIdx.x == 255) ctot[blockIdx.x] = part[255];
}
// block-parallel chunk-offset scan (SCAN_NCHUNK = 147 <= 256)
__global__ __launch_bounds__(256) void scan2(const int* __restrict__ ctot,
                                             int* __restrict__ coff) {
    __shared__ int part[256];
    int t = threadIdx.x;
    part[t] = (t < SCAN_NCHUNK) ? ctot[t] : 0;
    __syncthreads();
    for (int o = 1; o < 256; o <<= 1) {
        int x = (t >= o) ? part[t - o] : 0;
        __syncthreads();
        part[t] += x;
        __syncthreads();
    }
    if (t < SCAN_NCHUNK) coff[t] = t ? part[t - 1] : 0;
}
// adds chunk offsets; also initializes cur (drops the D2D copy launch)
__global__ __launch_bounds__(256) void scan3(int* __restrict__ off,
                                             const int* __restrict__ coff,
                                             int* __restrict__ cur) {
    int add = coff[blockIdx.x];
    int base = blockIdx.x * SCAN_CHUNK + threadIdx.x;
#pragma unroll
    for (int k = 0; k < 8; ++k) {
        int idx = base + k * 256;
        if (idx < SCAN_N) { int v = off[idx] + add; off[idx] = v; cur[idx] = v; }
    }
}

// ---- pure CSR scatter, thread per edge (purchase both directions + rel) ----
// purchase payload: {nbr | pos<<17,  f32 bits of e_time}
// rel payload:      {src+base | relid<<17, 0}
// No row loads, no dots here: the gather computes attention itself (it
// already has both operand rows in registers).
__global__ __launch_bounds__(256) void edges_scatter(
    const void* __restrict__ e_time,
    const int* __restrict__ e_uid, const int* __restrict__ e_iid,
    const int* __restrict__ pos_u, const int* __restrict__ pos_i,
    const int* __restrict__ eb_src, const int* __restrict__ eb_dst,
    const int* __restrict__ ec_src, const int* __restrict__ ec_dst,
    const int* __restrict__ er_src, const int* __restrict__ er_dst,
    int* __restrict__ cur, uint2* __restrict__ perm, const int* flagp) {
    int t = blockIdx.x * blockDim.x + threadIdx.x;
    if (t < NE) {
        int f = *flagp;
        int uid = e_uid[t], iid = e_iid[t];
        int pu = pos_u[t], pi = pos_i[t];
        unsigned tb = __float_as_uint(ldf(e_time, t, f));
        int s1 = atomicAdd(cur + uid, 1);
        perm[s1] = make_uint2((unsigned)iid | ((unsigned)pu << 17), tb);
        int s2 = atomicAdd(cur + NU + iid, 1);
        perm[s2] = make_uint2((unsigned)uid | ((unsigned)pi << 17), tb);
    } else if (t < NE + NEB) {
        int e = t - NE;
        int p = atomicAdd(cur + 2 * NU + eb_dst[e], 1);
        perm[p] = make_uint2((unsigned)eb_src[e], 0u);
    } else if (t < NE + NEB + NEC) {
        int e = t - NE - NEB;
        int p = atomicAdd(cur + 2 * NU + ec_dst[e], 1);
        perm[p] = make_uint2((unsigned)(ec_src[e] + NB_) | (1u << 17), 0u);
    } else if (t < NALL) {
        int e = t - NE - NEB - NEC;
        int p = atomicAdd(cur + 2 * NU + er_dst[e], 1);
        perm[p] = make_uint2((unsigned)(er_src[e] + NB_ + NC_) | (2u << 17), 0u);
    }
}

// ---- gather + attention: one vertex per 16-lane group (lane = 4 elems) ----
// Computes the dots/softmax in-place: the group's own row is loaded once,
// each neighbor row is gathered anyway for the weighted sum. Per neighbor:
// time-encode (4 cos), two dots via 4-step intra-group butterfly, 2 exps,
// then the weighted accumulation. All under the gather's load latency.
__global__ __launch_bounds__(256) void gather_all(
    const bf16_t* __restrict__ uh, const bf16_t* __restrict__ ih,
    const void* __restrict__ u_pos, const void* __restrict__ u_pos_k,
    const void* __restrict__ i_pos, const void* __restrict__ i_pos_k,
    const void* __restrict__ basis_freq, const void* __restrict__ phase_,
    const int* __restrict__ off, const uint2* __restrict__ perm,
    const bf16_t* __restrict__ fW,
    bf16_t* __restrict__ aggU, bf16_t* __restrict__ aggI,
    bf16_t* __restrict__ relb, const int* flagp) {
    int f = *flagp;
    int lane = threadIdx.x & 63;
    int l = lane & 15;                  // lane in group; covers elems [l*4, l*4+4)
    int gb = lane & 48;                 // group base lane within wave
    int l4 = l * 4;
    int v = blockIdx.x * 16 + (threadIdx.x >> 4);   // (NU+NI) % 16 == 0
    int phase = v >= NU;
    int vtx = phase ? v - NU : v;
    const bf16_t* other = phase ? uh : ih;
    const bf16_t* self_ = phase ? ih : uh;
    const void* pw = phase ? i_pos : u_pos;
    const void* pk = phase ? i_pos_k : u_pos_k;
    f32x4 ownv = bf4(self_ + (size_t)vtx * 64 + l4);
    f32x4 bfq = ldf4(basis_freq, l4, f);
    f32x4 phq = ldf4(phase_, l4, f);
    int j0 = off[v], j1 = off[v + 1];   // user segs [0,NU), item segs [NU,2NU)
    f32x4 a0 = (f32x4){0.f, 0.f, 0.f, 0.f}, a1 = a0;
    float s1 = 0.f, s2 = 0.f;
    for (int cb = j0; cb < j1; cb += 16) {
        int m = j1 - cb; if (m > 16) m = 16;
        uint2 pay = make_uint2(0u, 0u);
        if (l < m) pay = perm[cb + l];
        unsigned px0 = (unsigned)__shfl((int)pay.x, gb, 64);
        unsigned py0 = (unsigned)__shfl((int)pay.y, gb, 64);
        f32x4 ho0 = bf4(other + (size_t)(px0 & 0x1FFFF) * 64 + l4);
        f32x4 pk0 = ldf4(pk, (size_t)((px0 >> 17) & 63) * 64 + l4, f);
        f32x4 pw0 = ldf4(pw, (size_t)((px0 >> 17) & 63) * 64 + l4, f);
        for (int k = 0; k < m; ++k) {
            unsigned px1 = 0, py1 = 0;
            f32x4 ho1 = (f32x4){0.f, 0.f, 0.f, 0.f}, pk1 = ho1, pw1 = ho1;
            if (k + 1 < m) {
                px1 = (unsigned)__shfl((int)pay.x, gb + k + 1, 64);
                py1 = (unsigned)__shfl((int)pay.y, gb + k + 1, 64);
                ho1 = bf4(other + (size_t)(px1 & 0x1FFFF) * 64 + l4);
                pk1 = ldf4(pk, (size_t)((px1 >> 17) & 63) * 64 + l4, f);
                pw1 = ldf4(pw, (size_t)((px1 >> 17) & 63) * 64 + l4, f);
            }
            float tv = __uint_as_float(py0);
            float d_l = 0.f, d_s = 0.f;
#pragma unroll
            for (int q = 0; q < 4; ++q) {
                float te = __cosf(fmaf(tv, bfq[q], phq[q]));
                d_l = fmaf(ho0[q] + pk0[q] + te, ownv[q], d_l);
                d_s = fmaf(ho0[q], ownv[q], d_s);
            }
#pragma unroll
            for (int o = 1; o < 16; o <<= 1) {
                d_l += __shfl_xor(d_l, o, 64);
                d_s += __shfl_xor(d_s, o, 64);
            }
            float p1 = __expf(fminf(d_l * 0.125f, 30.f));
            float p2 = __expf(fminf(d_s * 0.125f, 30.f));
#pragma unroll
            for (int q = 0; q < 4; ++q) {
                a0[q] = fmaf(p1, ho0[q] + pw0[q], a0[q]);
                a1[q] = fmaf(p2, ho0[q], a1[q]);
            }
            s1 += p1; s2 += p2;
            px0 = px1; py0 = py1; ho0 = ho1; pk0 = pk1; pw0 = pw1;
        }
    }
    float inv1 = 1.f / (s1 + 1e-9f), inv2 = 1.f / (s2 + 1e-9f);
    bf16_t* aggRow = (phase ? aggI : aggU) + (size_t)vtx * 128;
    short4v o0, o1;
#pragma unroll
    for (int q = 0; q < 4; ++q) {
        o0[q] = (short)f2bu(a0[q] * inv1);
        o1[q] = (short)f2bu(a1[q] * inv2);
    }
    *(short4v*)(aggRow + l4) = o0;
    *(short4v*)(aggRow + 64 + l4) = o1;
    if (phase) {
        f32x4 r0 = (f32x4){0.f, 0.f, 0.f, 0.f}, r1 = r0, r2 = r0;
        int c0 = 0, c1 = 0, c2 = 0;
        int k0 = off[2 * NU + vtx], k1 = off[2 * NU + vtx + 1];
        for (int cb = k0; cb < k1; cb += 16) {
            int m = k1 - cb; if (m > 16) m = 16;
            unsigned px = 0u;
            if (l < m) px = perm[cb + l].x;
            unsigned u0 = (unsigned)__shfl((int)px, gb, 64);
            f32x4 fv0 = bf4(fW + (size_t)(u0 & 0x1FFFF) * 64 + l4);
            for (int k = 0; k < m; ++k) {
                unsigned u1 = 0;
                f32x4 fv1 = (f32x4){0.f, 0.f, 0.f, 0.f};
                if (k + 1 < m) {
                    u1 = (unsigned)__shfl((int)px, gb + k + 1, 64);
                    fv1 = bf4(fW + (size_t)(u1 & 0x1FFFF) * 64 + l4);
                }
                int r = (u0 >> 17) & 3;
                if (r == 0) {
#pragma unroll
                    for (int q = 0; q < 4; ++q) r0[q] += fv0[q];
                    c0++;
                } else if (r == 1) {
#pragma unroll
                    for (int q = 0; q < 4; ++q) r1[q] += fv0[q];
                    c1++;
                } else {
#pragma unroll
                    for (int q = 0; q < 4; ++q) r2[q] += fv0[q];
                    c2++;
                }
                u0 = u1; fv0 = fv1;
            }
        }
        float w0 = 1.f / fmaxf((float)c0, 1.f);
        float w1 = 1.f / fmaxf((float)c1, 1.f);
        float w2 = 1.f / fmaxf((float)c2, 1.f);
        short4v ro;
#pragma unroll
        for (int q = 0; q < 4; ++q)
            ro[q] = (short)f2bu(r0[q] * w0 + r1[q] * w1 + r2[q] * w2);
        *(short4v*)(relb + (size_t)vtx * 64 + l4) = ro;
    }
}

extern "C" void kernel_launch(void* const* d_in, const int* in_sizes, int n_in,
                              void* d_out, int out_size, void* d_ws, size_t ws_size,
                              hipStream_t stream) {
    const void* user_h     = d_in[0];
    const void* item_h     = d_in[1];
    const void* brand_feat = d_in[2];
    const void* cat_feat   = d_in[3];
    const void* rel_feat   = d_in[4];
    const void* Wu   = d_in[5];
    const void* Wi   = d_in[6];
    const void* Wb   = d_in[7];
    const void* Wc   = d_in[8];
    const void* Wr   = d_in[9];
    const void* Wg_u = d_in[10];
    const void* Wg_i = d_in[11];
    const void* u_pos   = d_in[12];
    const void* u_pos_k = d_in[13];
    const void* i_pos   = d_in[14];
    const void* i_pos_k = d_in[15];
    const void* basis_freq = d_in[16];
    const void* phase      = d_in[17];
    const void* Wr0 = d_in[18];
    const void* Wr1 = d_in[19];
    const void* Wr2 = d_in[20];
    const void* e_time = d_in[21];
    const int* e_iid  = (const int*)d_in[22];
    const int* e_uid  = (const int*)d_in[23];
    const int* pos_u  = (const int*)d_in[24];
    const int* pos_i  = (const int*)d_in[25];
    const int* eb_src = (const int*)d_in[26];
    const int* eb_dst = (const int*)d_in[27];
    const int* ec_src = (const int*)d_in[28];
    const int* ec_dst = (const int*)d_in[29];
    const int* er_src = (const int*)d_in[30];
    const int* er_dst = (const int*)d_in[31];

    char* base = (char*)d_ws;
    size_t off_b = 0;
    auto alloc = [&](size_t bytes) { size_t p = off_b; off_b = (off_b + bytes + 511) & ~(size_t)511; return p; };
    size_t o_flag  = alloc(512);
    size_t o_uh    = alloc((size_t)NU * 64 * 2);                 // 12.8 MB
    size_t o_ih    = alloc((size_t)NI * 64 * 2);                 // 12.8 MB
    size_t o_fW    = alloc((size_t)(NB_ + NC_ + NR_ + 64) * 64 * 2); // 7.3 MB
    size_t o_wcomb = alloc((size_t)3 * 4096 * 2);
    size_t o_deg   = alloc((size_t)SCAN_N * 4);
    size_t o_off   = alloc((size_t)SCAN_N * 4);
    size_t o_cur   = alloc((size_t)SCAN_N * 4);
    size_t o_ctot  = alloc((size_t)SCAN_NCHUNK * 4);
    size_t o_coff  = alloc((size_t)SCAN_NCHUNK * 4);
    size_t o_perm  = alloc((size_t)NPERM * 8);                   // 15.2 MB
    size_t o_aggU  = alloc((size_t)(NU + 64) * 128 * 2);         // 25.6 MB
    size_t o_aggI  = alloc((size_t)(NI + 64) * 128 * 2);         // 25.6 MB
    size_t o_relb  = alloc((size_t)(NI + 64) * 64 * 2);          // 12.8 MB

    int*    flagp = (int*)(base + o_flag);
    bf16_t* uh    = (bf16_t*)(base + o_uh);
    bf16_t* ih    = (bf16_t*)(base + o_ih);
    bf16_t* fW    = (bf16_t*)(base + o_fW);
    bf16_t* wcomb = (bf16_t*)(base + o_wcomb);
    int*    deg   = (int*)(base + o_deg);
    int*    offp  = (int*)(base + o_off);
    int*    cur   = (int*)(base + o_cur);
    int*    ctot  = (int*)(base + o_ctot);
    int*    coff  = (int*)(base + o_coff);
    uint2*  perm  = (uint2*)(base + o_perm);
    bf16_t* aggU  = (bf16_t*)(base + o_aggU);
    bf16_t* aggI  = (bf16_t*)(base + o_aggI);
    bf16_t* relb  = (bf16_t*)(base + o_relb);

    hipMemsetAsync(deg, 0, (size_t)SCAN_N * 4, stream);
    detect_dtype<<<1, 64, 0, stream>>>((const unsigned int*)basis_freq, flagp);

    combine_w<<<3, 256, 0, stream>>>(Wb, Wr0, Wc, Wr1, Wr, Wr2, wcomb, flagp);

    // transforms: uh = user_h@Wu, ih = item_h@Wi (one segmented launch)
    {
        GSeg su = {user_h, Wu, uh, nullptr, nullptr, NU, 0, 0, 0, 0};
        GSeg si = {item_h, Wi, ih, nullptr, nullptr, NI, 0, 0, 0, 0};
        gemm_multi<<<768, 256, 0, stream>>>(su, si, su, 2, 64, flagp);
    }
    // feature transforms: fW = feat @ wcomb (one segmented launch)
    {
        GSeg sb = {brand_feat, wcomb,        fW,                              nullptr, nullptr, NB_, 0, 0, 0, 1};
        GSeg sc = {cat_feat,   wcomb + 4096, fW + (size_t)NB_ * 64,           nullptr, nullptr, NC_, 0, 0, 0, 1};
        GSeg sr = {rel_feat,   wcomb + 8192, fW + (size_t)(NB_ + NC_) * 64,   nullptr, nullptr, NR_, 0, 0, 0, 1};
        gemm_multi<<<512, 256, 0, stream>>>(sb, sc, sr, 3, 64, flagp);
    }

    hist_all<<<(NALL + 255) / 256, 256, 0, stream>>>(e_uid, e_iid, eb_dst, ec_dst, er_dst, deg);
    scan1<<<SCAN_NCHUNK, 256, 0, stream>>>(deg, offp, ctot);
    scan2<<<1, 256, 0, stream>>>(ctot, coff);
    scan3<<<SCAN_NCHUNK, 256, 0, stream>>>(offp, coff, cur);

    // pure scatter: all 1.3M edges, thread per edge
    edges_scatter<<<(NALL + 255) / 256, 256, 0, stream>>>(e_time, e_uid, e_iid, pos_u, pos_i,
                                                          eb_src, eb_dst, ec_src, ec_dst,
                                                          er_src, er_dst, cur, perm, flagp);

    // gather + in-place attention; one vertex per 16-lane group
    gather_all<<<(NU + NI) / 16, 256, 0, stream>>>(uh, ih, u_pos, u_pos_k, i_pos, i_pos_k,
                                                   basis_freq, phase, offp, perm, fW,
                                                   aggU, aggI, relb, flagp);

    // final gated GEMMs + residual + elu, one segmented launch
    {
        GSeg su = {aggU, Wg_u, d_out, user_h, nullptr, NU, 0,  1, 1, 0};
        GSeg si = {aggI, Wg_i, d_out, item_h, relb,    NI, NU, 1, 1, 0};
        gemm_multi<<<512, 256, 0, stream>>>(su, si, su, 2, 128, flagp);
    }
}

// Round 7
// 573.501 us; speedup vs baseline: 1.2957x; 1.2957x over previous
//
#include <hip/hip_runtime.h>
#include <hip/hip_bf16.h>
#include <hip/hip_fp16.h>

typedef __hip_bfloat16 bf16_t;

#define NU 100000
#define NI 100000
#define NB_ 5000
#define NC_ 2000
#define NR_ 50000
#define NE 600000
#define NEB 100000
#define NEC 200000
#define NER 400000
#define NPERM (2 * NE + NEB + NEC + NER)   // 1,900,000
#define NRELE (NEB + NEC + NER)            // 700,000
#define NALL (NE + NRELE)
#define SCAN_N (2 * NU + NI + 1)
#define SCAN_CHUNK 2048
#define SCAN_NCHUNK ((SCAN_N + SCAN_CHUNK - 1) / SCAN_CHUNK)   // 147
#define PBLK 4096                          // purchase blocks in fused edge kernel
#define RBLK ((NRELE + 255) / 256)         // rel-scatter blocks

typedef __attribute__((ext_vector_type(8))) short short8;
typedef __attribute__((ext_vector_type(4))) short short4v;
typedef __attribute__((ext_vector_type(4))) float f32x4;

__device__ __forceinline__ float b2f(bf16_t x) { return __bfloat162float(x); }
__device__ __forceinline__ float sane(float x) { return isfinite(x) ? x : 0.f; }
__device__ __forceinline__ unsigned short f2bu(float x) {
    union { bf16_t b; unsigned short u; } c; c.b = __float2bfloat16(x); return c.u;
}

// dual-dtype load/store: external float tensors are f32 or bf16, per runtime flag
__device__ __forceinline__ float ldf(const void* p, size_t i, int f32) {
    return f32 ? ((const float*)p)[i] : __bfloat162float(((const bf16_t*)p)[i]);
}
__device__ __forceinline__ void stf(void* p, size_t i, float v, int f32) {
    if (f32) ((float*)p)[i] = v;
    else     ((bf16_t*)p)[i] = __float2bfloat16(v);
}

// 4-wide packed loads (i must be a multiple of 4 elements)
__device__ __forceinline__ f32x4 bf4(const bf16_t* p) {
    short4v s = *(const short4v*)p;
    f32x4 r;
#pragma unroll
    for (int q = 0; q < 4; ++q)
        r[q] = __uint_as_float(((unsigned)(unsigned short)s[q]) << 16);
    return r;
}
__device__ __forceinline__ f32x4 ldf4(const void* p, size_t i, int f32) {
    if (f32) return *(const f32x4*)((const float*)p + i);
    return bf4((const bf16_t*)p + i);
}

// 8-wide packed loads (i must be a multiple of 8 elements)
__device__ __forceinline__ void bf8(const bf16_t* p, float* o) {
    short8 s = *(const short8*)p;
#pragma unroll
    for (int q = 0; q < 8; ++q)
        o[q] = __uint_as_float(((unsigned)(unsigned short)s[q]) << 16);
}
__device__ __forceinline__ void ldf8(const void* p, size_t i, int f32, float* o) {
    if (f32) {
        f32x4 a = *(const f32x4*)((const float*)p + i);
        f32x4 b = *(const f32x4*)((const float*)p + i + 4);
#pragma unroll
        for (int q = 0; q < 4; ++q) { o[q] = a[q]; o[4 + q] = b[q]; }
    } else {
        bf8((const bf16_t*)p + i, o);
    }
}

// ---- dtype probe: basis_freq[0] == 1.0f exactly; f32 word = 0x3F800000 ----
__global__ void detect_dtype(const unsigned int* w, int* flag) {
    if (threadIdx.x == 0 && blockIdx.x == 0) *flag = (w[0] == 0x3F800000u) ? 1 : 0;
}

// ---- wcomb_r = W_feat_r @ Wr_r (bf16 out, internal); 48 blocks, 1 out/thread ----
__global__ __launch_bounds__(256) void combine_w(
    const void* Wb, const void* Wr0,
    const void* Wc, const void* Wr1,
    const void* Wr, const void* Wr2,
    bf16_t* out, const int* flagp) {
    int f = *flagp;
    int mat = blockIdx.x >> 4;          // 0..2
    int sub = blockIdx.x & 15;          // 0..15
    const void* A = mat == 0 ? Wb : (mat == 1 ? Wc : Wr);
    const void* B = mat == 0 ? Wr0 : (mat == 1 ? Wr1 : Wr2);
    int idx = sub * 256 + threadIdx.x;  // 0..4095
    int i = idx >> 6, j = idx & 63;
    float acc = 0.f;
    for (int k = 0; k < 64; ++k)
        acc = fmaf(ldf(A, i * 64 + k, f), ldf(B, k * 64 + j, f), acc);
    out[(size_t)mat * 4096 + idx] = __float2bfloat16(acc);
}

// ============================================================================
// Segmented multi-tile MFMA GEMM: up to 5 segments, each out=act(A@W[+bias]).
// Grid-strides over 64-row tiles; W staged in LDS once per segment per block
// (tile sequence is block-uniform -> barriers are safe).
// ============================================================================
struct GSeg {
    const void* A; const void* W; void* out;
    const void* hext; const bf16_t* relb;
    int M; int orow0; int out_mode; int a_internal; int w_internal;
};

__global__ __launch_bounds__(256) void gemm_multi(
    GSeg s0, GSeg s1, GSeg s2, GSeg s3, GSeg s4,
    int nseg, int K, const int* __restrict__ flagp) {
    __shared__ short WL[128 * 64];   // 16 KB max (K*64 used)
    int f = *flagp;
    int nt0 = (s0.M + 63) >> 6;
    int nt1 = (nseg > 1) ? ((s1.M + 63) >> 6) : 0;
    int nt2 = (nseg > 2) ? ((s2.M + 63) >> 6) : 0;
    int nt3 = (nseg > 3) ? ((s3.M + 63) >> 6) : 0;
    int nt4 = (nseg > 4) ? ((s4.M + 63) >> 6) : 0;
    int c0 = nt0, c1 = c0 + nt1, c2 = c1 + nt2, c3 = c2 + nt3;
    int ntT = c3 + nt4;
    int lane = threadIdx.x & 63;
    int wv = threadIdx.x >> 6;
    int q = lane >> 4, nl = lane & 15;
    int KK = K >> 5;
    int staged = -1;
    for (int tile = blockIdx.x; tile < ntT; tile += gridDim.x) {
        int sidx, t_in;
        if (tile < c0) { sidx = 0; t_in = tile; }
        else if (tile < c1) { sidx = 1; t_in = tile - c0; }
        else if (tile < c2) { sidx = 2; t_in = tile - c1; }
        else if (tile < c3) { sidx = 3; t_in = tile - c2; }
        else { sidx = 4; t_in = tile - c3; }
        const void* A; const void* W; void* out; const void* hext; const bf16_t* relb;
        int M, orow0, out_mode, a_int, w_int;
        if (sidx == 0) {
            A = s0.A; W = s0.W; out = s0.out; hext = s0.hext; relb = s0.relb;
            M = s0.M; orow0 = s0.orow0; out_mode = s0.out_mode; a_int = s0.a_internal; w_int = s0.w_internal;
        } else if (sidx == 1) {
            A = s1.A; W = s1.W; out = s1.out; hext = s1.hext; relb = s1.relb;
            M = s1.M; orow0 = s1.orow0; out_mode = s1.out_mode; a_int = s1.a_internal; w_int = s1.w_internal;
        } else if (sidx == 2) {
            A = s2.A; W = s2.W; out = s2.out; hext = s2.hext; relb = s2.relb;
            M = s2.M; orow0 = s2.orow0; out_mode = s2.out_mode; a_int = s2.a_internal; w_int = s2.w_internal;
        } else if (sidx == 3) {
            A = s3.A; W = s3.W; out = s3.out; hext = s3.hext; relb = s3.relb;
            M = s3.M; orow0 = s3.orow0; out_mode = s3.out_mode; a_int = s3.a_internal; w_int = s3.w_internal;
        } else {
            A = s4.A; W = s4.W; out = s4.out; hext = s4.hext; relb = s4.relb;
            M = s4.M; orow0 = s4.orow0; out_mode = s4.out_mode; a_int = s4.a_internal; w_int = s4.w_internal;
        }
        if (sidx != staged) {                       // block-uniform condition
            __syncthreads();                        // drain readers of old WL
            int w_f32 = w_int ? 0 : f;
            for (int i = threadIdx.x; i < K * 64; i += 256) {
                int j = i & 7, ln = (i >> 3) & 63, p = i >> 9;
                int kk4 = p >> 2, n0t = p & 3;
                int srow = kk4 * 32 + (ln >> 4) * 8 + j;
                int scol = n0t * 16 + (ln & 15);
                float wvv = w_f32 ? ((const float*)W)[srow * 64 + scol]
                                  : b2f(((const bf16_t*)W)[srow * 64 + scol]);
                WL[i] = (short)f2bu(wvv);
            }
            __syncthreads();
            staged = sidx;
        }
        int m0 = t_in * 64 + wv * 16;
        if (m0 < M) {
            int a_f32 = a_int ? 0 : f;
            int arow = m0 + nl; if (arow >= M) arow = M - 1;
            f32x4 acc[4];
#pragma unroll
            for (int t = 0; t < 4; ++t) acc[t] = (f32x4){0.f, 0.f, 0.f, 0.f};
            for (int kk4 = 0; kk4 < KK; ++kk4) {
                short8 af;
                size_t abase = (size_t)arow * K + kk4 * 32 + q * 8;
                if (a_f32) {
                    const f32x4* ap = (const f32x4*)((const float*)A + abase);
                    f32x4 x0 = ap[0], x1 = ap[1];
#pragma unroll
                    for (int j = 0; j < 4; ++j) {
                        af[j] = (short)f2bu(x0[j]);
                        af[4 + j] = (short)f2bu(x1[j]);
                    }
                } else {
                    af = *(const short8*)((const bf16_t*)A + abase);
                }
#pragma unroll
                for (int n0t = 0; n0t < 4; ++n0t) {
                    short8 bfr = *(const short8*)&WL[(((kk4 << 2) + n0t) * 64 + lane) * 8];
                    acc[n0t] = __builtin_amdgcn_mfma_f32_16x16x32_bf16(af, bfr, acc[n0t], 0, 0, 0);
                }
            }
#pragma unroll
            for (int n0t = 0; n0t < 4; ++n0t) {
#pragma unroll
                for (int r = 0; r < 4; ++r) {
                    int row = m0 + q * 4 + r;
                    if (row >= M) continue;
                    int col = n0t * 16 + nl;
                    float v = acc[n0t][r];
                    if (out_mode == 1) {
                        v += ldf(hext, (size_t)row * 64 + col, f);
                        if (relb) v += b2f(relb[(size_t)row * 64 + col]);
                        v = v > 0.f ? v : expm1f(v);
                        stf(out, (size_t)(row + orow0) * 64 + col, sane(v), f);
                    } else {
                        ((bf16_t*)out)[(size_t)row * 64 + col] = __float2bfloat16(v);
                    }
                }
            }
        }
    }
}

// ---- one-launch degree histogram over all edge sets ----
__global__ __launch_bounds__(256) void hist_all(
    const int* __restrict__ e_uid, const int* __restrict__ e_iid,
    const int* __restrict__ eb_dst, const int* __restrict__ ec_dst,
    const int* __restrict__ er_dst, int* __restrict__ deg) {
    int t = blockIdx.x * blockDim.x + threadIdx.x;
    if (t < NE) {
        atomicAdd(deg + e_uid[t], 1);
        atomicAdd(deg + NU + e_iid[t], 1);
    } else if (t < NE + NEB) {
        atomicAdd(deg + 2 * NU + eb_dst[t - NE], 1);
    } else if (t < NE + NEB + NEC) {
        atomicAdd(deg + 2 * NU + ec_dst[t - NE - NEB], 1);
    } else if (t < NALL) {
        atomicAdd(deg + 2 * NU + er_dst[t - NE - NEB - NEC], 1);
    }
}

// ---- exclusive scan over SCAN_N ints ----
__global__ __launch_bounds__(256) void scan1(const int* __restrict__ deg,
                                             int* __restrict__ off,
                                             int* __restrict__ ctot) {
    __shared__ int part[256];
    int base = blockIdx.x * SCAN_CHUNK + threadIdx.x * 8;
    int v[8]; int s = 0;
#pragma unroll
    for (int k = 0; k < 8; ++k) {
        int idx = base + k;
        v[k] = s;
        s += (idx < SCAN_N) ? deg[idx] : 0;
    }
    part[threadIdx.x] = s;
    __syncthreads();
    for (int o = 1; o < 256; o <<= 1) {
        int t = (threadIdx.x >= o) ? part[threadIdx.x - o] : 0;
        __syncthreads();
        part[threadIdx.x] += t;
        __syncthreads();
    }
    int texc = (threadIdx.x == 0) ? 0 : part[threadIdx.x - 1];
#pragma unroll
    for (int k = 0; k < 8; ++k) {
        int idx = base + k;
        if (idx < SCAN_N) off[idx] = texc + v[k];
    }
    if (threadIdx.x == 255) ctot[blockIdx.x] = part[255];
}
// merged scan2+scan3: every block redundantly scans ctot (147 ints) in LDS,
// picks its own chunk offset, applies it, and initializes cur.
__global__ __launch_bounds__(256) void scan23(int* __restrict__ off,
                                              const int* __restrict__ ctot,
                                              int* __restrict__ cur) {
    __shared__ int part[256];
    int t = threadIdx.x;
    part[t] = (t < SCAN_NCHUNK) ? ctot[t] : 0;
    __syncthreads();
    for (int o = 1; o < 256; o <<= 1) {
        int x = (t >= o) ? part[t - o] : 0;
        __syncthreads();
        part[t] += x;
        __syncthreads();
    }
    int add = blockIdx.x ? part[blockIdx.x - 1] : 0;
    int base = blockIdx.x * SCAN_CHUNK + t;
#pragma unroll
    for (int k = 0; k < 8; ++k) {
        int idx = base + k * 256;
        if (idx < SCAN_N) { int v = off[idx] + add; off[idx] = v; cur[idx] = v; }
    }
}

// ---- fused edge kernel: purchase (8 edges/wave, 8 lanes each) + rel scatter ----
// payload: {nbr | pos<<17,  f16(p_long) | f16(p_short)<<16}
__global__ __launch_bounds__(256) void edges_fused(
    const bf16_t* __restrict__ uh, const bf16_t* __restrict__ ih,
    const void* __restrict__ u_pos_k, const void* __restrict__ i_pos_k,
    const void* __restrict__ basis_freq, const void* __restrict__ phase_,
    const void* __restrict__ e_time,
    const int* __restrict__ e_uid, const int* __restrict__ e_iid,
    const int* __restrict__ pos_u, const int* __restrict__ pos_i,
    const int* __restrict__ eb_src, const int* __restrict__ eb_dst,
    const int* __restrict__ ec_src, const int* __restrict__ ec_dst,
    const int* __restrict__ er_src, const int* __restrict__ er_dst,
    int* __restrict__ cur, uint2* __restrict__ perm, const int* flagp) {
    if (blockIdx.x >= PBLK) {
        // relation edge payload scatter, thread per edge
        int t = (blockIdx.x - PBLK) * 256 + threadIdx.x;
        if (t < NEB) {
            int p = atomicAdd(cur + 2 * NU + eb_dst[t], 1);
            perm[p] = make_uint2((unsigned)eb_src[t], 0u);
        } else if (t < NEB + NEC) {
            int e = t - NEB;
            int p = atomicAdd(cur + 2 * NU + ec_dst[e], 1);
            perm[p] = make_uint2((unsigned)(ec_src[e] + NB_) | (1u << 17), 0u);
        } else if (t < NRELE) {
            int e = t - NEB - NEC;
            int p = atomicAdd(cur + 2 * NU + er_dst[e], 1);
            perm[p] = make_uint2((unsigned)(er_src[e] + NB_ + NC_) | (2u << 17), 0u);
        }
        return;
    }
    int f = *flagp;
    int lane = threadIdx.x & 63;
    int g = lane >> 3, l = lane & 7;   // 8 groups x 8 lanes; lane covers 8 elems (16B loads)
    float bfv[8], phv[8];
    ldf8(basis_freq, (size_t)l * 8, f, bfv);
    ldf8(phase_, (size_t)l * 8, f, phv);
    int w = (blockIdx.x * 256 + threadIdx.x) >> 6;
    const int NWAVE = PBLK * 4;
    for (int eb = w; eb < NE / 8; eb += NWAVE) {
        int e = eb * 8 + g;                 // NE % 8 == 0, always in range
        int uid = e_uid[e], iid = e_iid[e], pu = pos_u[e], pi = pos_i[e];
        float t = ldf(e_time, e, f);
        float hu[8], hi[8], pku[8], pki[8];
        bf8(uh + (size_t)uid * 64 + l * 8, hu);
        bf8(ih + (size_t)iid * 64 + l * 8, hi);
        ldf8(u_pos_k, (size_t)pu * 64 + l * 8, f, pku);
        ldf8(i_pos_k, (size_t)pi * 64 + l * 8, f, pki);
        float d_lu = 0.f, d_sh = 0.f, d_li = 0.f;
#pragma unroll
        for (int qq = 0; qq < 8; ++qq) {
            float te = __cosf(fmaf(t, bfv[qq], phv[qq]));
            d_lu = fmaf(hi[qq] + pku[qq] + te, hu[qq], d_lu);
            d_sh = fmaf(hi[qq], hu[qq], d_sh);
            d_li = fmaf(hu[qq] + pki[qq] + te, hi[qq], d_li);
        }
#pragma unroll
        for (int o = 1; o < 8; o <<= 1) {
            d_lu += __shfl_xor(d_lu, o, 64);
            d_sh += __shfl_xor(d_sh, o, 64);
            d_li += __shfl_xor(d_li, o, 64);
        }
        if (l == 0) {
            float p_lu = __expf(fminf(d_lu * 0.125f, 10.f));   // clamp protects f16 pack
            float p_sh = __expf(fminf(d_sh * 0.125f, 10.f));
            float p_li = __expf(fminf(d_li * 0.125f, 10.f));
            unsigned pkt_u = (unsigned)__half_as_ushort(__float2half(p_lu))
                           | ((unsigned)__half_as_ushort(__float2half(p_sh)) << 16);
            unsigned pkt_i = (unsigned)__half_as_ushort(__float2half(p_li))
                           | ((unsigned)__half_as_ushort(__float2half(p_sh)) << 16);
            int s1 = atomicAdd(cur + uid, 1);
            perm[s1] = make_uint2((unsigned)iid | ((unsigned)pu << 17), pkt_u);
            int s2 = atomicAdd(cur + NU + iid, 1);
            perm[s2] = make_uint2((unsigned)uid | ((unsigned)pi << 17), pkt_i);
        }
    }
}

// ---- gather: one vertex per 16-lane group (lane = 4 of 64 elements) ----
// No dot products here, so owning a whole vertex per group removes ALL
// cross-lane reduction: s1/s2 are group-broadcast scalars accumulated
// identically in every lane; epilogue is normalize+store only.
__global__ __launch_bounds__(256) void gather_all(
    const bf16_t* __restrict__ uh, const bf16_t* __restrict__ ih,
    const void* __restrict__ u_pos, const void* __restrict__ i_pos,
    const int* __restrict__ off, const uint2* __restrict__ perm,
    const bf16_t* __restrict__ fW,
    bf16_t* __restrict__ aggU, bf16_t* __restrict__ aggI,
    bf16_t* __restrict__ relb, const int* flagp) {
    int f = *flagp;
    int lane = threadIdx.x & 63;
    int l = lane & 15;                  // lane in group; covers elems [l*4, l*4+4)
    int gb = lane & 48;                 // group base lane within wave
    int l4 = l * 4;
    int v = blockIdx.x * 16 + (threadIdx.x >> 4);   // (NU+NI) % 16 == 0
    int phase = v >= NU;
    int vtx = phase ? v - NU : v;
    const bf16_t* other = phase ? uh : ih;
    const void* pv = phase ? i_pos : u_pos;
    int j0 = off[v], j1 = off[v + 1];   // user segs [0,NU), item segs [NU,2NU)
    f32x4 a0 = (f32x4){0.f, 0.f, 0.f, 0.f}, a1 = a0;
    float s1 = 0.f, s2 = 0.f;
    for (int cb = j0; cb < j1; cb += 16) {
        int m = j1 - cb; if (m > 16) m = 16;
        uint2 pay = make_uint2(0u, 0u);
        if (l < m) pay = perm[cb + l];
        unsigned px0 = (unsigned)__shfl((int)pay.x, gb, 64);
        unsigned py0 = (unsigned)__shfl((int)pay.y, gb, 64);
        f32x4 ho0 = bf4(other + (size_t)(px0 & 0x1FFFF) * 64 + l4);
        f32x4 pv0 = ldf4(pv, (size_t)((px0 >> 17) & 63) * 64 + l4, f);
        for (int k = 0; k < m; ++k) {
            unsigned px1 = 0, py1 = 0;
            f32x4 ho1 = (f32x4){0.f, 0.f, 0.f, 0.f}, pv1 = ho1;
            if (k + 1 < m) {
                px1 = (unsigned)__shfl((int)pay.x, gb + k + 1, 64);
                py1 = (unsigned)__shfl((int)pay.y, gb + k + 1, 64);
                ho1 = bf4(other + (size_t)(px1 & 0x1FFFF) * 64 + l4);
                pv1 = ldf4(pv, (size_t)((px1 >> 17) & 63) * 64 + l4, f);
            }
            float p1 = __half2float(__ushort_as_half((unsigned short)(py0 & 0xFFFF)));
            float p2 = __half2float(__ushort_as_half((unsigned short)(py0 >> 16)));
#pragma unroll
            for (int q = 0; q < 4; ++q) {
                a0[q] = fmaf(p1, ho0[q] + pv0[q], a0[q]);
                a1[q] = fmaf(p2, ho0[q], a1[q]);
            }
            s1 += p1; s2 += p2;
            px0 = px1; py0 = py1; ho0 = ho1; pv0 = pv1;
        }
    }
    float inv1 = 1.f / (s1 + 1e-9f), inv2 = 1.f / (s2 + 1e-9f);
    bf16_t* aggRow = (phase ? aggI : aggU) + (size_t)vtx * 128;
    short4v o0, o1;
#pragma unroll
    for (int q = 0; q < 4; ++q) {
        o0[q] = (short)f2bu(a0[q] * inv1);
        o1[q] = (short)f2bu(a1[q] * inv2);
    }
    *(short4v*)(aggRow + l4) = o0;
    *(short4v*)(aggRow + 64 + l4) = o1;
    if (phase) {
        f32x4 r0 = (f32x4){0.f, 0.f, 0.f, 0.f}, r1 = r0, r2 = r0;
        int c0 = 0, c1 = 0, c2 = 0;
        int k0 = off[2 * NU + vtx], k1 = off[2 * NU + vtx + 1];
        for (int cb = k0; cb < k1; cb += 16) {
            int m = k1 - cb; if (m > 16) m = 16;
            unsigned px = 0u;
            if (l < m) px = perm[cb + l].x;
            unsigned u0 = (unsigned)__shfl((int)px, gb, 64);
            f32x4 fv0 = bf4(fW + (size_t)(u0 & 0x1FFFF) * 64 + l4);
            for (int k = 0; k < m; ++k) {
                unsigned u1 = 0;
                f32x4 fv1 = (f32x4){0.f, 0.f, 0.f, 0.f};
                if (k + 1 < m) {
                    u1 = (unsigned)__shfl((int)px, gb + k + 1, 64);
                    fv1 = bf4(fW + (size_t)(u1 & 0x1FFFF) * 64 + l4);
                }
                int r = (u0 >> 17) & 3;
                if (r == 0) {
#pragma unroll
                    for (int q = 0; q < 4; ++q) r0[q] += fv0[q];
                    c0++;
                } else if (r == 1) {
#pragma unroll
                    for (int q = 0; q < 4; ++q) r1[q] += fv0[q];
                    c1++;
                } else {
#pragma unroll
                    for (int q = 0; q < 4; ++q) r2[q] += fv0[q];
                    c2++;
                }
                u0 = u1; fv0 = fv1;
            }
        }
        float w0 = 1.f / fmaxf((float)c0, 1.f);
        float w1 = 1.f / fmaxf((float)c1, 1.f);
        float w2 = 1.f / fmaxf((float)c2, 1.f);
        short4v ro;
#pragma unroll
        for (int q = 0; q < 4; ++q)
            ro[q] = (short)f2bu(r0[q] * w0 + r1[q] * w1 + r2[q] * w2);
        *(short4v*)(relb + (size_t)vtx * 64 + l4) = ro;
    }
}

extern "C" void kernel_launch(void* const* d_in, const int* in_sizes, int n_in,
                              void* d_out, int out_size, void* d_ws, size_t ws_size,
                              hipStream_t stream) {
    const void* user_h     = d_in[0];
    const void* item_h     = d_in[1];
    const void* brand_feat = d_in[2];
    const void* cat_feat   = d_in[3];
    const void* rel_feat   = d_in[4];
    const void* Wu   = d_in[5];
    const void* Wi   = d_in[6];
    const void* Wb   = d_in[7];
    const void* Wc   = d_in[8];
    const void* Wr   = d_in[9];
    const void* Wg_u = d_in[10];
    const void* Wg_i = d_in[11];
    const void* u_pos   = d_in[12];
    const void* u_pos_k = d_in[13];
    const void* i_pos   = d_in[14];
    const void* i_pos_k = d_in[15];
    const void* basis_freq = d_in[16];
    const void* phase      = d_in[17];
    const void* Wr0 = d_in[18];
    const void* Wr1 = d_in[19];
    const void* Wr2 = d_in[20];
    const void* e_time = d_in[21];
    const int* e_iid  = (const int*)d_in[22];
    const int* e_uid  = (const int*)d_in[23];
    const int* pos_u  = (const int*)d_in[24];
    const int* pos_i  = (const int*)d_in[25];
    const int* eb_src = (const int*)d_in[26];
    const int* eb_dst = (const int*)d_in[27];
    const int* ec_src = (const int*)d_in[28];
    const int* ec_dst = (const int*)d_in[29];
    const int* er_src = (const int*)d_in[30];
    const int* er_dst = (const int*)d_in[31];

    char* base = (char*)d_ws;
    size_t off_b = 0;
    auto alloc = [&](size_t bytes) { size_t p = off_b; off_b = (off_b + bytes + 511) & ~(size_t)511; return p; };
    size_t o_flag  = alloc(512);
    size_t o_uh    = alloc((size_t)NU * 64 * 2);                 // 12.8 MB
    size_t o_ih    = alloc((size_t)NI * 64 * 2);                 // 12.8 MB
    size_t o_fW    = alloc((size_t)(NB_ + NC_ + NR_ + 64) * 64 * 2); // 7.3 MB
    size_t o_wcomb = alloc((size_t)3 * 4096 * 2);
    size_t o_deg   = alloc((size_t)SCAN_N * 4);
    size_t o_off   = alloc((size_t)SCAN_N * 4);
    size_t o_cur   = alloc((size_t)SCAN_N * 4);
    size_t o_ctot  = alloc((size_t)SCAN_NCHUNK * 4);
    size_t o_perm  = alloc((size_t)NPERM * 8);                   // 15.2 MB
    size_t o_aggU  = alloc((size_t)(NU + 64) * 128 * 2);         // 25.6 MB
    size_t o_aggI  = alloc((size_t)(NI + 64) * 128 * 2);         // 25.6 MB
    size_t o_relb  = alloc((size_t)(NI + 64) * 64 * 2);          // 12.8 MB

    int*    flagp = (int*)(base + o_flag);
    bf16_t* uh    = (bf16_t*)(base + o_uh);
    bf16_t* ih    = (bf16_t*)(base + o_ih);
    bf16_t* fW    = (bf16_t*)(base + o_fW);
    bf16_t* wcomb = (bf16_t*)(base + o_wcomb);
    int*    deg   = (int*)(base + o_deg);
    int*    offp  = (int*)(base + o_off);
    int*    cur   = (int*)(base + o_cur);
    int*    ctot  = (int*)(base + o_ctot);
    uint2*  perm  = (uint2*)(base + o_perm);
    bf16_t* aggU  = (bf16_t*)(base + o_aggU);
    bf16_t* aggI  = (bf16_t*)(base + o_aggI);
    bf16_t* relb  = (bf16_t*)(base + o_relb);

    hipMemsetAsync(deg, 0, (size_t)SCAN_N * 4, stream);
    detect_dtype<<<1, 64, 0, stream>>>((const unsigned int*)basis_freq, flagp);

    combine_w<<<48, 256, 0, stream>>>(Wb, Wr0, Wc, Wr1, Wr, Wr2, wcomb, flagp);

    // all K=64 GEMMs in ONE 5-segment launch: uh, ih, then the 3 feature sets
    {
        GSeg su = {user_h,     Wu,           uh,                            nullptr, nullptr, NU,  0, 0, 0, 0};
        GSeg si = {item_h,     Wi,           ih,                            nullptr, nullptr, NI,  0, 0, 0, 0};
        GSeg sb = {brand_feat, wcomb,        fW,                            nullptr, nullptr, NB_, 0, 0, 0, 1};
        GSeg sc = {cat_feat,   wcomb + 4096, fW + (size_t)NB_ * 64,         nullptr, nullptr, NC_, 0, 0, 0, 1};
        GSeg sr = {rel_feat,   wcomb + 8192, fW + (size_t)(NB_ + NC_) * 64, nullptr, nullptr, NR_, 0, 0, 0, 1};
        gemm_multi<<<1024, 256, 0, stream>>>(su, si, sb, sc, sr, 5, 64, flagp);
    }

    hist_all<<<(NALL + 255) / 256, 256, 0, stream>>>(e_uid, e_iid, eb_dst, ec_dst, er_dst, deg);
    scan1<<<SCAN_NCHUNK, 256, 0, stream>>>(deg, offp, ctot);
    scan23<<<SCAN_NCHUNK, 256, 0, stream>>>(offp, ctot, cur);

    edges_fused<<<PBLK + RBLK, 256, 0, stream>>>(uh, ih, u_pos_k, i_pos_k, basis_freq, phase,
                                                 e_time, e_uid, e_iid, pos_u, pos_i,
                                                 eb_src, eb_dst, ec_src, ec_dst,
                                                 er_src, er_dst, cur, perm, flagp);

    // both gather phases in one launch; one vertex per 16-lane group
    gather_all<<<(NU + NI) / 16, 256, 0, stream>>>(uh, ih, u_pos, i_pos, offp, perm, fW,
                                                   aggU, aggI, relb, flagp);

    // final gated GEMMs + residual + elu, one segmented launch
    {
        GSeg su = {aggU, Wg_u, d_out, user_h, nullptr, NU, 0,  1, 1, 0};
        GSeg si = {aggI, Wg_i, d_out, item_h, relb,    NI, NU, 1, 1, 0};
        gemm_multi<<<512, 256, 0, stream>>>(su, si, su, su, su, 2, 128, flagp);
    }
}

// Round 8
// 514.247 us; speedup vs baseline: 1.4450x; 1.1152x over previous
//
#include <hip/hip_runtime.h>
#include <hip/hip_bf16.h>
#include <hip/hip_fp16.h>

typedef __hip_bfloat16 bf16_t;

#define NU 100000
#define NI 100000
#define NB_ 5000
#define NC_ 2000
#define NR_ 50000
#define NE 600000
#define NEB 100000
#define NEC 200000
#define NER 400000
#define NPERM (2 * NE + NEB + NEC + NER)   // 1,900,000
#define NRELE (NEB + NEC + NER)            // 700,000
#define NALL (NE + NRELE)
#define SCAN_N (2 * NU + NI + 1)
#define SCAN_CHUNK 2048
#define SCAN_NCHUNK ((SCAN_N + SCAN_CHUNK - 1) / SCAN_CHUNK)   // 147
#define PBLK 8192                          // purchase blocks in fused edge kernel
#define RBLK ((NRELE + 255) / 256)         // rel-scatter blocks

// LDS row strides (shorts) chosen for 16B alignment + conflict-freedom
#define AGS 136
#define RLS 68

typedef __attribute__((ext_vector_type(8))) short short8;
typedef __attribute__((ext_vector_type(4))) short short4v;
typedef __attribute__((ext_vector_type(4))) float f32x4;

__device__ __forceinline__ float b2f(bf16_t x) { return __bfloat162float(x); }
__device__ __forceinline__ float sane(float x) { return isfinite(x) ? x : 0.f; }
__device__ __forceinline__ unsigned short f2bu(float x) {
    union { bf16_t b; unsigned short u; } c; c.b = __float2bfloat16(x); return c.u;
}

// dual-dtype load/store: external float tensors are f32 or bf16, per runtime flag
__device__ __forceinline__ float ldf(const void* p, size_t i, int f32) {
    return f32 ? ((const float*)p)[i] : __bfloat162float(((const bf16_t*)p)[i]);
}
__device__ __forceinline__ void stf(void* p, size_t i, float v, int f32) {
    if (f32) ((float*)p)[i] = v;
    else     ((bf16_t*)p)[i] = __float2bfloat16(v);
}

// 4-wide packed loads (i must be a multiple of 4 elements)
__device__ __forceinline__ f32x4 bf4(const bf16_t* p) {
    short4v s = *(const short4v*)p;
    f32x4 r;
#pragma unroll
    for (int q = 0; q < 4; ++q)
        r[q] = __uint_as_float(((unsigned)(unsigned short)s[q]) << 16);
    return r;
}
__device__ __forceinline__ f32x4 ldf4(const void* p, size_t i, int f32) {
    if (f32) return *(const f32x4*)((const float*)p + i);
    return bf4((const bf16_t*)p + i);
}

// 8-wide packed loads (i must be a multiple of 8 elements)
__device__ __forceinline__ void bf8(const bf16_t* p, float* o) {
    short8 s = *(const short8*)p;
#pragma unroll
    for (int q = 0; q < 8; ++q)
        o[q] = __uint_as_float(((unsigned)(unsigned short)s[q]) << 16);
}
__device__ __forceinline__ void ldf8(const void* p, size_t i, int f32, float* o) {
    if (f32) {
        f32x4 a = *(const f32x4*)((const float*)p + i);
        f32x4 b = *(const f32x4*)((const float*)p + i + 4);
#pragma unroll
        for (int q = 0; q < 4; ++q) { o[q] = a[q]; o[4 + q] = b[q]; }
    } else {
        bf8((const bf16_t*)p + i, o);
    }
}

// ---- dtype probe: basis_freq[0] == 1.0f exactly; f32 word = 0x3F800000 ----
__global__ void detect_dtype(const unsigned int* w, int* flag) {
    if (threadIdx.x == 0 && blockIdx.x == 0) *flag = (w[0] == 0x3F800000u) ? 1 : 0;
}

// ---- blocks 0..47: wcomb_r = W_feat_r @ Wr_r (bf16, 1 out/thread)
// ---- blocks 48..111: pre-swizzle Wg_u/Wg_i into MFMA B-frag layout ----
__global__ __launch_bounds__(256) void combine_w(
    const void* Wb, const void* Wr0,
    const void* Wc, const void* Wr1,
    const void* Wr, const void* Wr2,
    const void* Wg_u, const void* Wg_i,
    bf16_t* out, bf16_t* wgsw, const int* flagp) {
    int f = *flagp;
    if (blockIdx.x < 48) {
        int mat = blockIdx.x >> 4;          // 0..2
        int sub = blockIdx.x & 15;          // 0..15
        const void* A = mat == 0 ? Wb : (mat == 1 ? Wc : Wr);
        const void* B = mat == 0 ? Wr0 : (mat == 1 ? Wr1 : Wr2);
        int idx = sub * 256 + threadIdx.x;  // 0..4095
        int i = idx >> 6, j = idx & 63;
        float acc = 0.f;
        for (int k = 0; k < 64; ++k)
            acc = fmaf(ldf(A, i * 64 + k, f), ldf(B, k * 64 + j, f), acc);
        out[(size_t)mat * 4096 + idx] = __float2bfloat16(acc);
    } else {
        // swizzle: wgsw[mat*8192 + ((kk4*4+n0t)*64+ln)*8+j] = Wg[srow][scol]
        int t = (blockIdx.x - 48) * 256 + threadIdx.x;   // 0..16383
        int mat = t >> 13;                  // 0: Wg_u, 1: Wg_i
        int i = t & 8191;
        int j = i & 7, ln = (i >> 3) & 63, p = i >> 9;   // p 0..15
        int kk4 = p >> 2, n0t = p & 3;
        int srow = kk4 * 32 + (ln >> 4) * 8 + j;         // 0..127
        int scol = n0t * 16 + (ln & 15);
        const void* src = mat ? Wg_i : Wg_u;
        wgsw[(size_t)mat * 8192 + i] = __float2bfloat16(ldf(src, (size_t)srow * 64 + scol, f));
    }
}

// ============================================================================
// Segmented multi-tile MFMA GEMM (K=64 transforms): up to 5 segments.
// Grid-strides over 64-row tiles; W staged in LDS once per segment per block.
// ============================================================================
struct GSeg {
    const void* A; const void* W; void* out;
    int M; int a_internal; int w_internal;
};

__global__ __launch_bounds__(256) void gemm_multi(
    GSeg s0, GSeg s1, GSeg s2, GSeg s3, GSeg s4,
    int nseg, const int* __restrict__ flagp) {
    const int K = 64;
    __shared__ short WL[64 * 64];
    int f = *flagp;
    int nt0 = (s0.M + 63) >> 6;
    int nt1 = (nseg > 1) ? ((s1.M + 63) >> 6) : 0;
    int nt2 = (nseg > 2) ? ((s2.M + 63) >> 6) : 0;
    int nt3 = (nseg > 3) ? ((s3.M + 63) >> 6) : 0;
    int nt4 = (nseg > 4) ? ((s4.M + 63) >> 6) : 0;
    int c0 = nt0, c1 = c0 + nt1, c2 = c1 + nt2, c3 = c2 + nt3;
    int ntT = c3 + nt4;
    int lane = threadIdx.x & 63;
    int wv = threadIdx.x >> 6;
    int q = lane >> 4, nl = lane & 15;
    int staged = -1;
    for (int tile = blockIdx.x; tile < ntT; tile += gridDim.x) {
        int sidx, t_in;
        if (tile < c0) { sidx = 0; t_in = tile; }
        else if (tile < c1) { sidx = 1; t_in = tile - c0; }
        else if (tile < c2) { sidx = 2; t_in = tile - c1; }
        else if (tile < c3) { sidx = 3; t_in = tile - c2; }
        else { sidx = 4; t_in = tile - c3; }
        const void* A; const void* W; void* out; int M, a_int, w_int;
        if (sidx == 0)      { A = s0.A; W = s0.W; out = s0.out; M = s0.M; a_int = s0.a_internal; w_int = s0.w_internal; }
        else if (sidx == 1) { A = s1.A; W = s1.W; out = s1.out; M = s1.M; a_int = s1.a_internal; w_int = s1.w_internal; }
        else if (sidx == 2) { A = s2.A; W = s2.W; out = s2.out; M = s2.M; a_int = s2.a_internal; w_int = s2.w_internal; }
        else if (sidx == 3) { A = s3.A; W = s3.W; out = s3.out; M = s3.M; a_int = s3.a_internal; w_int = s3.w_internal; }
        else                { A = s4.A; W = s4.W; out = s4.out; M = s4.M; a_int = s4.a_internal; w_int = s4.w_internal; }
        if (sidx != staged) {                       // block-uniform condition
            __syncthreads();                        // drain readers of old WL
            int w_f32 = w_int ? 0 : f;
            for (int i = threadIdx.x; i < K * 64; i += 256) {
                int j = i & 7, ln = (i >> 3) & 63, p = i >> 9;
                int kk4 = p >> 2, n0t = p & 3;
                int srow = kk4 * 32 + (ln >> 4) * 8 + j;
                int scol = n0t * 16 + (ln & 15);
                float wvv = w_f32 ? ((const float*)W)[srow * 64 + scol]
                                  : b2f(((const bf16_t*)W)[srow * 64 + scol]);
                WL[i] = (short)f2bu(wvv);
            }
            __syncthreads();
            staged = sidx;
        }
        int m0 = t_in * 64 + wv * 16;
        if (m0 < M) {
            int a_f32 = a_int ? 0 : f;
            int arow = m0 + nl; if (arow >= M) arow = M - 1;
            f32x4 acc[4];
#pragma unroll
            for (int t = 0; t < 4; ++t) acc[t] = (f32x4){0.f, 0.f, 0.f, 0.f};
            for (int kk4 = 0; kk4 < 2; ++kk4) {
                short8 af;
                size_t abase = (size_t)arow * K + kk4 * 32 + q * 8;
                if (a_f32) {
                    const f32x4* ap = (const f32x4*)((const float*)A + abase);
                    f32x4 x0 = ap[0], x1 = ap[1];
#pragma unroll
                    for (int j = 0; j < 4; ++j) {
                        af[j] = (short)f2bu(x0[j]);
                        af[4 + j] = (short)f2bu(x1[j]);
                    }
                } else {
                    af = *(const short8*)((const bf16_t*)A + abase);
                }
#pragma unroll
                for (int n0t = 0; n0t < 4; ++n0t) {
                    short8 bfr = *(const short8*)&WL[(((kk4 << 2) + n0t) * 64 + lane) * 8];
                    acc[n0t] = __builtin_amdgcn_mfma_f32_16x16x32_bf16(af, bfr, acc[n0t], 0, 0, 0);
                }
            }
#pragma unroll
            for (int n0t = 0; n0t < 4; ++n0t) {
#pragma unroll
                for (int r = 0; r < 4; ++r) {
                    int row = m0 + q * 4 + r;
                    if (row >= M) continue;
                    int col = n0t * 16 + nl;
                    ((bf16_t*)out)[(size_t)row * 64 + col] = __float2bfloat16(acc[n0t][r]);
                }
            }
        }
    }
}

// ---- one-launch degree histogram over all edge sets ----
__global__ __launch_bounds__(256) void hist_all(
    const int* __restrict__ e_uid, const int* __restrict__ e_iid,
    const int* __restrict__ eb_dst, const int* __restrict__ ec_dst,
    const int* __restrict__ er_dst, int* __restrict__ deg) {
    int t = blockIdx.x * blockDim.x + threadIdx.x;
    if (t < NE) {
        atomicAdd(deg + e_uid[t], 1);
        atomicAdd(deg + NU + e_iid[t], 1);
    } else if (t < NE + NEB) {
        atomicAdd(deg + 2 * NU + eb_dst[t - NE], 1);
    } else if (t < NE + NEB + NEC) {
        atomicAdd(deg + 2 * NU + ec_dst[t - NE - NEB], 1);
    } else if (t < NALL) {
        atomicAdd(deg + 2 * NU + er_dst[t - NE - NEB - NEC], 1);
    }
}

// ---- exclusive scan over SCAN_N ints ----
__global__ __launch_bounds__(256) void scan1(const int* __restrict__ deg,
                                             int* __restrict__ off,
                                             int* __restrict__ ctot) {
    __shared__ int part[256];
    int base = blockIdx.x * SCAN_CHUNK + threadIdx.x * 8;
    int v[8]; int s = 0;
#pragma unroll
    for (int k = 0; k < 8; ++k) {
        int idx = base + k;
        v[k] = s;
        s += (idx < SCAN_N) ? deg[idx] : 0;
    }
    part[threadIdx.x] = s;
    __syncthreads();
    for (int o = 1; o < 256; o <<= 1) {
        int t = (threadIdx.x >= o) ? part[threadIdx.x - o] : 0;
        __syncthreads();
        part[threadIdx.x] += t;
        __syncthreads();
    }
    int texc = (threadIdx.x == 0) ? 0 : part[threadIdx.x - 1];
#pragma unroll
    for (int k = 0; k < 8; ++k) {
        int idx = base + k;
        if (idx < SCAN_N) off[idx] = texc + v[k];
    }
    if (threadIdx.x == 255) ctot[blockIdx.x] = part[255];
}
// merged scan2+scan3: every block redundantly scans ctot (147 ints) in LDS,
// picks its own chunk offset, applies it, and initializes cur.
__global__ __launch_bounds__(256) void scan23(int* __restrict__ off,
                                              const int* __restrict__ ctot,
                                              int* __restrict__ cur) {
    __shared__ int part[256];
    int t = threadIdx.x;
    part[t] = (t < SCAN_NCHUNK) ? ctot[t] : 0;
    __syncthreads();
    for (int o = 1; o < 256; o <<= 1) {
        int x = (t >= o) ? part[t - o] : 0;
        __syncthreads();
        part[t] += x;
        __syncthreads();
    }
    int add = blockIdx.x ? part[blockIdx.x - 1] : 0;
    int base = blockIdx.x * SCAN_CHUNK + t;
#pragma unroll
    for (int k = 0; k < 8; ++k) {
        int idx = base + k * 256;
        if (idx < SCAN_N) { int v = off[idx] + add; off[idx] = v; cur[idx] = v; }
    }
}

// ---- fused edge kernel: purchase (8 edges/wave, 8 lanes each) + rel scatter ----
// payload: {nbr | pos<<17,  f16(p_long) | f16(p_short)<<16}
// The two directions' atomic->store chains run on lanes 0 and 1 in parallel.
__global__ __launch_bounds__(256) void edges_fused(
    const bf16_t* __restrict__ uh, const bf16_t* __restrict__ ih,
    const void* __restrict__ u_pos_k, const void* __restrict__ i_pos_k,
    const void* __restrict__ basis_freq, const void* __restrict__ phase_,
    const void* __restrict__ e_time,
    const int* __restrict__ e_uid, const int* __restrict__ e_iid,
    const int* __restrict__ pos_u, const int* __restrict__ pos_i,
    const int* __restrict__ eb_src, const int* __restrict__ eb_dst,
    const int* __restrict__ ec_src, const int* __restrict__ ec_dst,
    const int* __restrict__ er_src, const int* __restrict__ er_dst,
    int* __restrict__ cur, uint2* __restrict__ perm, const int* flagp) {
    if (blockIdx.x >= PBLK) {
        // relation edge payload scatter, thread per edge
        int t = (blockIdx.x - PBLK) * 256 + threadIdx.x;
        if (t < NEB) {
            int p = atomicAdd(cur + 2 * NU + eb_dst[t], 1);
            perm[p] = make_uint2((unsigned)eb_src[t], 0u);
        } else if (t < NEB + NEC) {
            int e = t - NEB;
            int p = atomicAdd(cur + 2 * NU + ec_dst[e], 1);
            perm[p] = make_uint2((unsigned)(ec_src[e] + NB_) | (1u << 17), 0u);
        } else if (t < NRELE) {
            int e = t - NEB - NEC;
            int p = atomicAdd(cur + 2 * NU + er_dst[e], 1);
            perm[p] = make_uint2((unsigned)(er_src[e] + NB_ + NC_) | (2u << 17), 0u);
        }
        return;
    }
    int f = *flagp;
    int lane = threadIdx.x & 63;
    int g = lane >> 3, l = lane & 7;   // 8 groups x 8 lanes; lane covers 8 elems (16B loads)
    float bfv[8], phv[8];
    ldf8(basis_freq, (size_t)l * 8, f, bfv);
    ldf8(phase_, (size_t)l * 8, f, phv);
    int w = (blockIdx.x * 256 + threadIdx.x) >> 6;
    const int NWAVE = PBLK * 4;
    for (int eb = w; eb < NE / 8; eb += NWAVE) {
        int e = eb * 8 + g;                 // NE % 8 == 0, always in range
        int uid = e_uid[e], iid = e_iid[e], pu = pos_u[e], pi = pos_i[e];
        float t = ldf(e_time, e, f);
        float hu[8], hi[8], pku[8], pki[8];
        bf8(uh + (size_t)uid * 64 + l * 8, hu);
        bf8(ih + (size_t)iid * 64 + l * 8, hi);
        ldf8(u_pos_k, (size_t)pu * 64 + l * 8, f, pku);
        ldf8(i_pos_k, (size_t)pi * 64 + l * 8, f, pki);
        float d_lu = 0.f, d_sh = 0.f, d_li = 0.f;
#pragma unroll
        for (int qq = 0; qq < 8; ++qq) {
            float te = __cosf(fmaf(t, bfv[qq], phv[qq]));
            d_lu = fmaf(hi[qq] + pku[qq] + te, hu[qq], d_lu);
            d_sh = fmaf(hi[qq], hu[qq], d_sh);
            d_li = fmaf(hu[qq] + pki[qq] + te, hi[qq], d_li);
        }
#pragma unroll
        for (int o = 1; o < 8; o <<= 1) {
            d_lu += __shfl_xor(d_lu, o, 64);
            d_sh += __shfl_xor(d_sh, o, 64);
            d_li += __shfl_xor(d_li, o, 64);
        }
        if (l == 0) {
            float p_lu = __expf(fminf(d_lu * 0.125f, 10.f));   // clamp protects f16 pack
            float p_sh = __expf(fminf(d_sh * 0.125f, 10.f));
            unsigned pkt_u = (unsigned)__half_as_ushort(__float2half(p_lu))
                           | ((unsigned)__half_as_ushort(__float2half(p_sh)) << 16);
            int s1 = atomicAdd(cur + uid, 1);
            perm[s1] = make_uint2((unsigned)iid | ((unsigned)pu << 17), pkt_u);
        } else if (l == 1) {
            float p_li = __expf(fminf(d_li * 0.125f, 10.f));
            float p_sh = __expf(fminf(d_sh * 0.125f, 10.f));
            unsigned pkt_i = (unsigned)__half_as_ushort(__float2half(p_li))
                           | ((unsigned)__half_as_ushort(__float2half(p_sh)) << 16);
            int s2 = atomicAdd(cur + NU + iid, 1);
            perm[s2] = make_uint2((unsigned)uid | ((unsigned)pi << 17), pkt_i);
        }
    }
}

// ============================================================================
// Fused gather + final GEMM + residual + elu.
// Block = 16 consecutive vertices (one per 16-lane group). Gather exactly as
// before; agg rows (and relv) deposited in LDS; one barrier; then each wave
// computes the 16x16 output slice n0t=wave via 4 MFMAs with pre-swizzled Wg
// B-fragments read from global (L2-hot, no LDS staging). Epilogue adds
// hext (+relb), elu, stores to d_out.
// ============================================================================
__global__ __launch_bounds__(256) void gather_gemm(
    const bf16_t* __restrict__ uh, const bf16_t* __restrict__ ih,
    const void* __restrict__ u_pos, const void* __restrict__ i_pos,
    const int* __restrict__ off, const uint2* __restrict__ perm,
    const bf16_t* __restrict__ fW, const bf16_t* __restrict__ wgsw,
    const void* __restrict__ user_h, const void* __restrict__ item_h,
    void* __restrict__ d_out, const int* flagp) {
    __shared__ short AG[16 * AGS];       // agg tile [16][128], stride 136
    __shared__ short RL[16 * RLS];       // relv tile [16][64], stride 68
    int f = *flagp;
    int lane = threadIdx.x & 63;
    int l = lane & 15;                  // lane in group; covers elems [l*4, l*4+4)
    int gb = lane & 48;                 // group base lane within wave
    int l4 = l * 4;
    int grp = threadIdx.x >> 4;         // 0..15 = row in tile
    int v0 = blockIdx.x * 16;
    int v = v0 + grp;                   // (NU+NI) % 16 == 0; block phase-uniform
    int phase = v >= NU;
    int vtx = phase ? v - NU : v;
    const bf16_t* other = phase ? uh : ih;
    const void* pv = phase ? i_pos : u_pos;
    int j0 = off[v], j1 = off[v + 1];   // user segs [0,NU), item segs [NU,2NU)
    f32x4 a0 = (f32x4){0.f, 0.f, 0.f, 0.f}, a1 = a0;
    float s1 = 0.f, s2 = 0.f;
    for (int cb = j0; cb < j1; cb += 16) {
        int m = j1 - cb; if (m > 16) m = 16;
        uint2 pay = make_uint2(0u, 0u);
        if (l < m) pay = perm[cb + l];
        unsigned px0 = (unsigned)__shfl((int)pay.x, gb, 64);
        unsigned py0 = (unsigned)__shfl((int)pay.y, gb, 64);
        f32x4 ho0 = bf4(other + (size_t)(px0 & 0x1FFFF) * 64 + l4);
        f32x4 pv0 = ldf4(pv, (size_t)((px0 >> 17) & 63) * 64 + l4, f);
        for (int k = 0; k < m; ++k) {
            unsigned px1 = 0, py1 = 0;
            f32x4 ho1 = (f32x4){0.f, 0.f, 0.f, 0.f}, pv1 = ho1;
            if (k + 1 < m) {
                px1 = (unsigned)__shfl((int)pay.x, gb + k + 1, 64);
                py1 = (unsigned)__shfl((int)pay.y, gb + k + 1, 64);
                ho1 = bf4(other + (size_t)(px1 & 0x1FFFF) * 64 + l4);
                pv1 = ldf4(pv, (size_t)((px1 >> 17) & 63) * 64 + l4, f);
            }
            float p1 = __half2float(__ushort_as_half((unsigned short)(py0 & 0xFFFF)));
            float p2 = __half2float(__ushort_as_half((unsigned short)(py0 >> 16)));
#pragma unroll
            for (int q = 0; q < 4; ++q) {
                a0[q] = fmaf(p1, ho0[q] + pv0[q], a0[q]);
                a1[q] = fmaf(p2, ho0[q], a1[q]);
            }
            s1 += p1; s2 += p2;
            px0 = px1; py0 = py1; ho0 = ho1; pv0 = pv1;
        }
    }
    float inv1 = 1.f / (s1 + 1e-9f), inv2 = 1.f / (s2 + 1e-9f);
    {
        short4v o0, o1;
#pragma unroll
        for (int q = 0; q < 4; ++q) {
            o0[q] = (short)f2bu(a0[q] * inv1);
            o1[q] = (short)f2bu(a1[q] * inv2);
        }
        *(short4v*)&AG[grp * AGS + l4] = o0;
        *(short4v*)&AG[grp * AGS + 64 + l4] = o1;
    }
    if (phase) {
        f32x4 r0 = (f32x4){0.f, 0.f, 0.f, 0.f}, r1 = r0, r2 = r0;
        int c0 = 0, c1 = 0, c2 = 0;
        int k0 = off[2 * NU + vtx], k1 = off[2 * NU + vtx + 1];
        for (int cb = k0; cb < k1; cb += 16) {
            int m = k1 - cb; if (m > 16) m = 16;
            unsigned px = 0u;
            if (l < m) px = perm[cb + l].x;
            unsigned u0 = (unsigned)__shfl((int)px, gb, 64);
            f32x4 fv0 = bf4(fW + (size_t)(u0 & 0x1FFFF) * 64 + l4);
            for (int k = 0; k < m; ++k) {
                unsigned u1 = 0;
                f32x4 fv1 = (f32x4){0.f, 0.f, 0.f, 0.f};
                if (k + 1 < m) {
                    u1 = (unsigned)__shfl((int)px, gb + k + 1, 64);
                    fv1 = bf4(fW + (size_t)(u1 & 0x1FFFF) * 64 + l4);
                }
                int r = (u0 >> 17) & 3;
                if (r == 0) {
#pragma unroll
                    for (int q = 0; q < 4; ++q) r0[q] += fv0[q];
                    c0++;
                } else if (r == 1) {
#pragma unroll
                    for (int q = 0; q < 4; ++q) r1[q] += fv0[q];
                    c1++;
                } else {
#pragma unroll
                    for (int q = 0; q < 4; ++q) r2[q] += fv0[q];
                    c2++;
                }
                u0 = u1; fv0 = fv1;
            }
        }
        float w0 = 1.f / fmaxf((float)c0, 1.f);
        float w1 = 1.f / fmaxf((float)c1, 1.f);
        float w2 = 1.f / fmaxf((float)c2, 1.f);
        short4v ro;
#pragma unroll
        for (int q = 0; q < 4; ++q)
            ro[q] = (short)f2bu(r0[q] * w0 + r1[q] * w1 + r2[q] * w2);
        *(short4v*)&RL[grp * RLS + l4] = ro;
    }
    __syncthreads();
    // ---- MFMA: wave wv computes cols [wv*16, wv*16+16) of the 16x64 tile ----
    int wv = threadIdx.x >> 6;
    int q = lane >> 4, nl = lane & 15;
    const bf16_t* wg = wgsw + (phase ? 8192 : 0);
    f32x4 acc = (f32x4){0.f, 0.f, 0.f, 0.f};
#pragma unroll
    for (int kk = 0; kk < 4; ++kk) {
        short8 af = *(const short8*)&AG[nl * AGS + kk * 32 + q * 8];
        short8 bfr = *(const short8*)&wg[(((kk << 2) + wv) * 64 + lane) * 8];
        acc = __builtin_amdgcn_mfma_f32_16x16x32_bf16(af, bfr, acc, 0, 0, 0);
    }
    const void* hext = phase ? item_h : user_h;
    int hbase = phase ? v0 - NU : v0;
#pragma unroll
    for (int r = 0; r < 4; ++r) {
        int row = q * 4 + r;               // vertex within tile
        int col = wv * 16 + nl;
        float val = acc[r];
        val += ldf(hext, (size_t)(hbase + row) * 64 + col, f);
        if (phase) val += b2f(((const bf16_t*)RL)[row * RLS + col]);
        val = val > 0.f ? val : expm1f(val);
        stf(d_out, (size_t)(v0 + row) * 64 + col, sane(val), f);
    }
}

extern "C" void kernel_launch(void* const* d_in, const int* in_sizes, int n_in,
                              void* d_out, int out_size, void* d_ws, size_t ws_size,
                              hipStream_t stream) {
    const void* user_h     = d_in[0];
    const void* item_h     = d_in[1];
    const void* brand_feat = d_in[2];
    const void* cat_feat   = d_in[3];
    const void* rel_feat   = d_in[4];
    const void* Wu   = d_in[5];
    const void* Wi   = d_in[6];
    const void* Wb   = d_in[7];
    const void* Wc   = d_in[8];
    const void* Wr   = d_in[9];
    const void* Wg_u = d_in[10];
    const void* Wg_i = d_in[11];
    const void* u_pos   = d_in[12];
    const void* u_pos_k = d_in[13];
    const void* i_pos   = d_in[14];
    const void* i_pos_k = d_in[15];
    const void* basis_freq = d_in[16];
    const void* phase      = d_in[17];
    const void* Wr0 = d_in[18];
    const void* Wr1 = d_in[19];
    const void* Wr2 = d_in[20];
    const void* e_time = d_in[21];
    const int* e_iid  = (const int*)d_in[22];
    const int* e_uid  = (const int*)d_in[23];
    const int* pos_u  = (const int*)d_in[24];
    const int* pos_i  = (const int*)d_in[25];
    const int* eb_src = (const int*)d_in[26];
    const int* eb_dst = (const int*)d_in[27];
    const int* ec_src = (const int*)d_in[28];
    const int* ec_dst = (const int*)d_in[29];
    const int* er_src = (const int*)d_in[30];
    const int* er_dst = (const int*)d_in[31];

    char* base = (char*)d_ws;
    size_t off_b = 0;
    auto alloc = [&](size_t bytes) { size_t p = off_b; off_b = (off_b + bytes + 511) & ~(size_t)511; return p; };
    size_t o_flag  = alloc(512);
    size_t o_uh    = alloc((size_t)NU * 64 * 2);                 // 12.8 MB
    size_t o_ih    = alloc((size_t)NI * 64 * 2);                 // 12.8 MB
    size_t o_fW    = alloc((size_t)(NB_ + NC_ + NR_ + 64) * 64 * 2); // 7.3 MB
    size_t o_wcomb = alloc((size_t)3 * 4096 * 2);
    size_t o_wgsw  = alloc((size_t)2 * 8192 * 2);                // 32 KB
    size_t o_deg   = alloc((size_t)SCAN_N * 4);
    size_t o_off   = alloc((size_t)SCAN_N * 4);
    size_t o_cur   = alloc((size_t)SCAN_N * 4);
    size_t o_ctot  = alloc((size_t)SCAN_NCHUNK * 4);
    size_t o_perm  = alloc((size_t)NPERM * 8);                   // 15.2 MB

    int*    flagp = (int*)(base + o_flag);
    bf16_t* uh    = (bf16_t*)(base + o_uh);
    bf16_t* ih    = (bf16_t*)(base + o_ih);
    bf16_t* fW    = (bf16_t*)(base + o_fW);
    bf16_t* wcomb = (bf16_t*)(base + o_wcomb);
    bf16_t* wgsw  = (bf16_t*)(base + o_wgsw);
    int*    deg   = (int*)(base + o_deg);
    int*    offp  = (int*)(base + o_off);
    int*    cur   = (int*)(base + o_cur);
    int*    ctot  = (int*)(base + o_ctot);
    uint2*  perm  = (uint2*)(base + o_perm);

    hipMemsetAsync(deg, 0, (size_t)SCAN_N * 4, stream);
    detect_dtype<<<1, 64, 0, stream>>>((const unsigned int*)basis_freq, flagp);

    combine_w<<<112, 256, 0, stream>>>(Wb, Wr0, Wc, Wr1, Wr, Wr2, Wg_u, Wg_i,
                                       wcomb, wgsw, flagp);

    // all K=64 GEMMs in ONE 5-segment launch: uh, ih, then the 3 feature sets
    {
        GSeg su = {user_h,     Wu,           uh,                            NU,  0, 0};
        GSeg si = {item_h,     Wi,           ih,                            NI,  0, 0};
        GSeg sb = {brand_feat, wcomb,        fW,                            NB_, 0, 1};
        GSeg sc = {cat_feat,   wcomb + 4096, fW + (size_t)NB_ * 64,         NC_, 0, 1};
        GSeg sr = {rel_feat,   wcomb + 8192, fW + (size_t)(NB_ + NC_) * 64, NR_, 0, 1};
        gemm_multi<<<1024, 256, 0, stream>>>(su, si, sb, sc, sr, 5, flagp);
    }

    hist_all<<<(NALL + 255) / 256, 256, 0, stream>>>(e_uid, e_iid, eb_dst, ec_dst, er_dst, deg);
    scan1<<<SCAN_NCHUNK, 256, 0, stream>>>(deg, offp, ctot);
    scan23<<<SCAN_NCHUNK, 256, 0, stream>>>(offp, ctot, cur);

    edges_fused<<<PBLK + RBLK, 256, 0, stream>>>(uh, ih, u_pos_k, i_pos_k, basis_freq, phase,
                                                 e_time, e_uid, e_iid, pos_u, pos_i,
                                                 eb_src, eb_dst, ec_src, ec_dst,
                                                 er_src, er_dst, cur, perm, flagp);

    // gather + final GEMM + residual + elu, single launch
    gather_gemm<<<(NU + NI) / 16, 256, 0, stream>>>(uh, ih, u_pos, i_pos, offp, perm, fW,
                                                    wgsw, user_h, item_h, d_out, flagp);
}

// Round 9
// 498.790 us; speedup vs baseline: 1.4898x; 1.0310x over previous
//
#include <hip/hip_runtime.h>
#include <hip/hip_bf16.h>
#include <hip/hip_fp16.h>

typedef __hip_bfloat16 bf16_t;

#define NU 100000
#define NI 100000
#define NB_ 5000
#define NC_ 2000
#define NR_ 50000
#define NE 600000
#define NEB 100000
#define NEC 200000
#define NER 400000
#define NPERM (2 * NE + NEB + NEC + NER)   // 1,900,000
#define NRELE (NEB + NEC + NER)            // 700,000
#define NALL (NE + NRELE)
#define SCAN_N (2 * NU + NI + 1)
#define SCAN_CHUNK 2048
#define SCAN_NCHUNK ((SCAN_N + SCAN_CHUNK - 1) / SCAN_CHUNK)   // 147
#define PBLK 4096                          // purchase blocks in fused edge kernel
#define RBLK ((NRELE + 255) / 256)         // rel-scatter blocks
#define GEMM_BLKS 1024                     // gemm blocks in merged gemm+hist launch
#define HIST_BLKS 2048

// LDS row strides (shorts) chosen for 16B alignment + conflict-freedom
#define AGS 136
#define RLS 68

typedef __attribute__((ext_vector_type(8))) short short8;
typedef __attribute__((ext_vector_type(4))) short short4v;
typedef __attribute__((ext_vector_type(4))) float f32x4;

__device__ __forceinline__ float b2f(bf16_t x) { return __bfloat162float(x); }
__device__ __forceinline__ float sane(float x) { return isfinite(x) ? x : 0.f; }
__device__ __forceinline__ unsigned short f2bu(float x) {
    union { bf16_t b; unsigned short u; } c; c.b = __float2bfloat16(x); return c.u;
}

// dual-dtype load/store: external float tensors are f32 or bf16, per runtime flag
__device__ __forceinline__ float ldf(const void* p, size_t i, int f32) {
    return f32 ? ((const float*)p)[i] : __bfloat162float(((const bf16_t*)p)[i]);
}
__device__ __forceinline__ void stf(void* p, size_t i, float v, int f32) {
    if (f32) ((float*)p)[i] = v;
    else     ((bf16_t*)p)[i] = __float2bfloat16(v);
}

// 4-wide packed loads (i must be a multiple of 4 elements)
__device__ __forceinline__ f32x4 bf4(const bf16_t* p) {
    short4v s = *(const short4v*)p;
    f32x4 r;
#pragma unroll
    for (int q = 0; q < 4; ++q)
        r[q] = __uint_as_float(((unsigned)(unsigned short)s[q]) << 16);
    return r;
}
__device__ __forceinline__ f32x4 ldf4(const void* p, size_t i, int f32) {
    if (f32) return *(const f32x4*)((const float*)p + i);
    return bf4((const bf16_t*)p + i);
}

// 8-wide packed loads (i must be a multiple of 8 elements)
__device__ __forceinline__ void bf8(const bf16_t* p, float* o) {
    short8 s = *(const short8*)p;
#pragma unroll
    for (int q = 0; q < 8; ++q)
        o[q] = __uint_as_float(((unsigned)(unsigned short)s[q]) << 16);
}
__device__ __forceinline__ void ldf8(const void* p, size_t i, int f32, float* o) {
    if (f32) {
        f32x4 a = *(const f32x4*)((const float*)p + i);
        f32x4 b = *(const f32x4*)((const float*)p + i + 4);
#pragma unroll
        for (int q = 0; q < 4; ++q) { o[q] = a[q]; o[4 + q] = b[q]; }
    } else {
        bf8((const bf16_t*)p + i, o);
    }
}

// ---- dtype probe: basis_freq[0] == 1.0f exactly; f32 word = 0x3F800000 ----
__global__ void detect_dtype(const unsigned int* w, int* flag) {
    if (threadIdx.x == 0 && blockIdx.x == 0) *flag = (w[0] == 0x3F800000u) ? 1 : 0;
}

// ---- blocks 0..47: wcomb_r = W_feat_r @ Wr_r (bf16, 1 out/thread)
// ---- blocks 48..111: pre-swizzle Wg_u/Wg_i into MFMA B-frag layout ----
__global__ __launch_bounds__(256) void combine_w(
    const void* Wb, const void* Wr0,
    const void* Wc, const void* Wr1,
    const void* Wr, const void* Wr2,
    const void* Wg_u, const void* Wg_i,
    bf16_t* out, bf16_t* wgsw, const int* flagp) {
    int f = *flagp;
    if (blockIdx.x < 48) {
        int mat = blockIdx.x >> 4;          // 0..2
        int sub = blockIdx.x & 15;          // 0..15
        const void* A = mat == 0 ? Wb : (mat == 1 ? Wc : Wr);
        const void* B = mat == 0 ? Wr0 : (mat == 1 ? Wr1 : Wr2);
        int idx = sub * 256 + threadIdx.x;  // 0..4095
        int i = idx >> 6, j = idx & 63;
        float acc = 0.f;
        for (int k = 0; k < 64; ++k)
            acc = fmaf(ldf(A, i * 64 + k, f), ldf(B, k * 64 + j, f), acc);
        out[(size_t)mat * 4096 + idx] = __float2bfloat16(acc);
    } else {
        // swizzle: wgsw[mat*8192 + ((kk4*4+n0t)*64+ln)*8+j] = Wg[srow][scol]
        int t = (blockIdx.x - 48) * 256 + threadIdx.x;   // 0..16383
        int mat = t >> 13;                  // 0: Wg_u, 1: Wg_i
        int i = t & 8191;
        int j = i & 7, ln = (i >> 3) & 63, p = i >> 9;   // p 0..15
        int kk4 = p >> 2, n0t = p & 3;
        int srow = kk4 * 32 + (ln >> 4) * 8 + j;         // 0..127
        int scol = n0t * 16 + (ln & 15);
        const void* src = mat ? Wg_i : Wg_u;
        wgsw[(size_t)mat * 8192 + i] = __float2bfloat16(ldf(src, (size_t)srow * 64 + scol, f));
    }
}

// ============================================================================
// Merged launch: blocks [0,GEMM_BLKS) run the segmented K=64 MFMA GEMM
// (up to 5 segments, W staged in LDS per segment); blocks >= GEMM_BLKS run
// the degree histogram grid-strided. Independent work, co-scheduled so the
// histogram's atomic latency hides under MFMA waves.
// ============================================================================
struct GSeg {
    const void* A; const void* W; void* out;
    int M; int a_internal; int w_internal;
};

__global__ __launch_bounds__(256) void gemm_hist(
    GSeg s0, GSeg s1, GSeg s2, GSeg s3, GSeg s4,
    int nseg, const int* __restrict__ flagp,
    const int* __restrict__ e_uid, const int* __restrict__ e_iid,
    const int* __restrict__ eb_dst, const int* __restrict__ ec_dst,
    const int* __restrict__ er_dst, int* __restrict__ deg) {
    if (blockIdx.x >= GEMM_BLKS) {
        int tid = (blockIdx.x - GEMM_BLKS) * 256 + threadIdx.x;
        const int nthr = HIST_BLKS * 256;
        for (int t = tid; t < NALL; t += nthr) {
            if (t < NE) {
                atomicAdd(deg + e_uid[t], 1);
                atomicAdd(deg + NU + e_iid[t], 1);
            } else if (t < NE + NEB) {
                atomicAdd(deg + 2 * NU + eb_dst[t - NE], 1);
            } else if (t < NE + NEB + NEC) {
                atomicAdd(deg + 2 * NU + ec_dst[t - NE - NEB], 1);
            } else {
                atomicAdd(deg + 2 * NU + er_dst[t - NE - NEB - NEC], 1);
            }
        }
        return;
    }
    const int K = 64;
    __shared__ short WL[64 * 64];
    int f = *flagp;
    int nt0 = (s0.M + 63) >> 6;
    int nt1 = (nseg > 1) ? ((s1.M + 63) >> 6) : 0;
    int nt2 = (nseg > 2) ? ((s2.M + 63) >> 6) : 0;
    int nt3 = (nseg > 3) ? ((s3.M + 63) >> 6) : 0;
    int nt4 = (nseg > 4) ? ((s4.M + 63) >> 6) : 0;
    int c0 = nt0, c1 = c0 + nt1, c2 = c1 + nt2, c3 = c2 + nt3;
    int ntT = c3 + nt4;
    int lane = threadIdx.x & 63;
    int wv = threadIdx.x >> 6;
    int q = lane >> 4, nl = lane & 15;
    int staged = -1;
    for (int tile = blockIdx.x; tile < ntT; tile += GEMM_BLKS) {
        int sidx, t_in;
        if (tile < c0) { sidx = 0; t_in = tile; }
        else if (tile < c1) { sidx = 1; t_in = tile - c0; }
        else if (tile < c2) { sidx = 2; t_in = tile - c1; }
        else if (tile < c3) { sidx = 3; t_in = tile - c2; }
        else { sidx = 4; t_in = tile - c3; }
        const void* A; const void* W; void* out; int M, a_int, w_int;
        if (sidx == 0)      { A = s0.A; W = s0.W; out = s0.out; M = s0.M; a_int = s0.a_internal; w_int = s0.w_internal; }
        else if (sidx == 1) { A = s1.A; W = s1.W; out = s1.out; M = s1.M; a_int = s1.a_internal; w_int = s1.w_internal; }
        else if (sidx == 2) { A = s2.A; W = s2.W; out = s2.out; M = s2.M; a_int = s2.a_internal; w_int = s2.w_internal; }
        else if (sidx == 3) { A = s3.A; W = s3.W; out = s3.out; M = s3.M; a_int = s3.a_internal; w_int = s3.w_internal; }
        else                { A = s4.A; W = s4.W; out = s4.out; M = s4.M; a_int = s4.a_internal; w_int = s4.w_internal; }
        if (sidx != staged) {                       // block-uniform condition
            __syncthreads();                        // drain readers of old WL
            int w_f32 = w_int ? 0 : f;
            for (int i = threadIdx.x; i < K * 64; i += 256) {
                int j = i & 7, ln = (i >> 3) & 63, p = i >> 9;
                int kk4 = p >> 2, n0t = p & 3;
                int srow = kk4 * 32 + (ln >> 4) * 8 + j;
                int scol = n0t * 16 + (ln & 15);
                float wvv = w_f32 ? ((const float*)W)[srow * 64 + scol]
                                  : b2f(((const bf16_t*)W)[srow * 64 + scol]);
                WL[i] = (short)f2bu(wvv);
            }
            __syncthreads();
            staged = sidx;
        }
        int m0 = t_in * 64 + wv * 16;
        if (m0 < M) {
            int a_f32 = a_int ? 0 : f;
            int arow = m0 + nl; if (arow >= M) arow = M - 1;
            f32x4 acc[4];
#pragma unroll
            for (int t = 0; t < 4; ++t) acc[t] = (f32x4){0.f, 0.f, 0.f, 0.f};
            for (int kk4 = 0; kk4 < 2; ++kk4) {
                short8 af;
                size_t abase = (size_t)arow * K + kk4 * 32 + q * 8;
                if (a_f32) {
                    const f32x4* ap = (const f32x4*)((const float*)A + abase);
                    f32x4 x0 = ap[0], x1 = ap[1];
#pragma unroll
                    for (int j = 0; j < 4; ++j) {
                        af[j] = (short)f2bu(x0[j]);
                        af[4 + j] = (short)f2bu(x1[j]);
                    }
                } else {
                    af = *(const short8*)((const bf16_t*)A + abase);
                }
#pragma unroll
                for (int n0t = 0; n0t < 4; ++n0t) {
                    short8 bfr = *(const short8*)&WL[(((kk4 << 2) + n0t) * 64 + lane) * 8];
                    acc[n0t] = __builtin_amdgcn_mfma_f32_16x16x32_bf16(af, bfr, acc[n0t], 0, 0, 0);
                }
            }
#pragma unroll
            for (int n0t = 0; n0t < 4; ++n0t) {
#pragma unroll
                for (int r = 0; r < 4; ++r) {
                    int row = m0 + q * 4 + r;
                    if (row >= M) continue;
                    int col = n0t * 16 + nl;
                    ((bf16_t*)out)[(size_t)row * 64 + col] = __float2bfloat16(acc[n0t][r]);
                }
            }
        }
    }
}

// ---- exclusive scan over SCAN_N ints ----
__global__ __launch_bounds__(256) void scan1(const int* __restrict__ deg,
                                             int* __restrict__ off,
                                             int* __restrict__ ctot) {
    __shared__ int part[256];
    int base = blockIdx.x * SCAN_CHUNK + threadIdx.x * 8;
    int v[8]; int s = 0;
#pragma unroll
    for (int k = 0; k < 8; ++k) {
        int idx = base + k;
        v[k] = s;
        s += (idx < SCAN_N) ? deg[idx] : 0;
    }
    part[threadIdx.x] = s;
    __syncthreads();
    for (int o = 1; o < 256; o <<= 1) {
        int t = (threadIdx.x >= o) ? part[threadIdx.x - o] : 0;
        __syncthreads();
        part[threadIdx.x] += t;
        __syncthreads();
    }
    int texc = (threadIdx.x == 0) ? 0 : part[threadIdx.x - 1];
#pragma unroll
    for (int k = 0; k < 8; ++k) {
        int idx = base + k;
        if (idx < SCAN_N) off[idx] = texc + v[k];
    }
    if (threadIdx.x == 255) ctot[blockIdx.x] = part[255];
}
// merged scan2+scan3: every block redundantly scans ctot (147 ints) in LDS,
// picks its own chunk offset, applies it, and initializes cur.
__global__ __launch_bounds__(256) void scan23(int* __restrict__ off,
                                              const int* __restrict__ ctot,
                                              int* __restrict__ cur) {
    __shared__ int part[256];
    int t = threadIdx.x;
    part[t] = (t < SCAN_NCHUNK) ? ctot[t] : 0;
    __syncthreads();
    for (int o = 1; o < 256; o <<= 1) {
        int x = (t >= o) ? part[t - o] : 0;
        __syncthreads();
        part[t] += x;
        __syncthreads();
    }
    int add = blockIdx.x ? part[blockIdx.x - 1] : 0;
    int base = blockIdx.x * SCAN_CHUNK + t;
#pragma unroll
    for (int k = 0; k < 8; ++k) {
        int idx = base + k * 256;
        if (idx < SCAN_N) { int v = off[idx] + add; off[idx] = v; cur[idx] = v; }
    }
}

// ---- fused edge kernel: purchase (8 edges/wave, 8 lanes each) + rel scatter ----
// payload: {nbr | pos<<17,  f16(p_long) | f16(p_short)<<16}
// Slot atomics are issued FIRST (lanes 0/1, depend only on uid/iid); their
// ~500-cycle round trip hides under the row loads + cos/fma + butterfly that
// follow. The payload stores consume the slots at the end of the iteration.
__global__ __launch_bounds__(256) void edges_fused(
    const bf16_t* __restrict__ uh, const bf16_t* __restrict__ ih,
    const void* __restrict__ u_pos_k, const void* __restrict__ i_pos_k,
    const void* __restrict__ basis_freq, const void* __restrict__ phase_,
    const void* __restrict__ e_time,
    const int* __restrict__ e_uid, const int* __restrict__ e_iid,
    const int* __restrict__ pos_u, const int* __restrict__ pos_i,
    const int* __restrict__ eb_src, const int* __restrict__ eb_dst,
    const int* __restrict__ ec_src, const int* __restrict__ ec_dst,
    const int* __restrict__ er_src, const int* __restrict__ er_dst,
    int* __restrict__ cur, uint2* __restrict__ perm, const int* flagp) {
    if (blockIdx.x >= PBLK) {
        // relation edge payload scatter, thread per edge
        int t = (blockIdx.x - PBLK) * 256 + threadIdx.x;
        if (t < NEB) {
            int p = atomicAdd(cur + 2 * NU + eb_dst[t], 1);
            perm[p] = make_uint2((unsigned)eb_src[t], 0u);
        } else if (t < NEB + NEC) {
            int e = t - NEB;
            int p = atomicAdd(cur + 2 * NU + ec_dst[e], 1);
            perm[p] = make_uint2((unsigned)(ec_src[e] + NB_) | (1u << 17), 0u);
        } else if (t < NRELE) {
            int e = t - NEB - NEC;
            int p = atomicAdd(cur + 2 * NU + er_dst[e], 1);
            perm[p] = make_uint2((unsigned)(er_src[e] + NB_ + NC_) | (2u << 17), 0u);
        }
        return;
    }
    int f = *flagp;
    int lane = threadIdx.x & 63;
    int g = lane >> 3, l = lane & 7;   // 8 groups x 8 lanes; lane covers 8 elems (16B loads)
    float bfv[8], phv[8];
    ldf8(basis_freq, (size_t)l * 8, f, bfv);
    ldf8(phase_, (size_t)l * 8, f, phv);
    int w = (blockIdx.x * 256 + threadIdx.x) >> 6;
    const int NWAVE = PBLK * 4;
    for (int eb = w; eb < NE / 8; eb += NWAVE) {
        int e = eb * 8 + g;                 // NE % 8 == 0, always in range
        int uid = e_uid[e], iid = e_iid[e], pu = pos_u[e], pi = pos_i[e];
        // ---- issue slot atomics early; no dependence on the math below ----
        int slot = 0;
        if (l == 0)      slot = atomicAdd(cur + uid, 1);
        else if (l == 1) slot = atomicAdd(cur + NU + iid, 1);
        float t = ldf(e_time, e, f);
        float hu[8], hi[8], pku[8], pki[8];
        bf8(uh + (size_t)uid * 64 + l * 8, hu);
        bf8(ih + (size_t)iid * 64 + l * 8, hi);
        ldf8(u_pos_k, (size_t)pu * 64 + l * 8, f, pku);
        ldf8(i_pos_k, (size_t)pi * 64 + l * 8, f, pki);
        float d_lu = 0.f, d_sh = 0.f, d_li = 0.f;
#pragma unroll
        for (int qq = 0; qq < 8; ++qq) {
            float te = __cosf(fmaf(t, bfv[qq], phv[qq]));
            d_lu = fmaf(hi[qq] + pku[qq] + te, hu[qq], d_lu);
            d_sh = fmaf(hi[qq], hu[qq], d_sh);
            d_li = fmaf(hu[qq] + pki[qq] + te, hi[qq], d_li);
        }
#pragma unroll
        for (int o = 1; o < 8; o <<= 1) {
            d_lu += __shfl_xor(d_lu, o, 64);
            d_sh += __shfl_xor(d_sh, o, 64);
            d_li += __shfl_xor(d_li, o, 64);
        }
        if (l == 0) {
            float p_lu = __expf(fminf(d_lu * 0.125f, 10.f));   // clamp protects f16 pack
            float p_sh = __expf(fminf(d_sh * 0.125f, 10.f));
            unsigned pkt_u = (unsigned)__half_as_ushort(__float2half(p_lu))
                           | ((unsigned)__half_as_ushort(__float2half(p_sh)) << 16);
            perm[slot] = make_uint2((unsigned)iid | ((unsigned)pu << 17), pkt_u);
        } else if (l == 1) {
            float p_li = __expf(fminf(d_li * 0.125f, 10.f));
            float p_sh = __expf(fminf(d_sh * 0.125f, 10.f));
            unsigned pkt_i = (unsigned)__half_as_ushort(__float2half(p_li))
                           | ((unsigned)__half_as_ushort(__float2half(p_sh)) << 16);
            perm[slot] = make_uint2((unsigned)uid | ((unsigned)pi << 17), pkt_i);
        }
    }
}

// ============================================================================
// Fused gather + final GEMM + residual + elu.
// Block = 16 consecutive vertices (one per 16-lane group). Gather exactly as
// before; agg rows (and relv) deposited in LDS; one barrier; then each wave
// computes the 16x16 output slice n0t=wave via 4 MFMAs with pre-swizzled Wg
// B-fragments read from global (L2-hot, no LDS staging). Epilogue adds
// hext (+relb), elu, stores to d_out.
// ============================================================================
__global__ __launch_bounds__(256) void gather_gemm(
    const bf16_t* __restrict__ uh, const bf16_t* __restrict__ ih,
    const void* __restrict__ u_pos, const void* __restrict__ i_pos,
    const int* __restrict__ off, const uint2* __restrict__ perm,
    const bf16_t* __restrict__ fW, const bf16_t* __restrict__ wgsw,
    const void* __restrict__ user_h, const void* __restrict__ item_h,
    void* __restrict__ d_out, const int* flagp) {
    __shared__ short AG[16 * AGS];       // agg tile [16][128], stride 136
    __shared__ short RL[16 * RLS];       // relv tile [16][64], stride 68
    int f = *flagp;
    int lane = threadIdx.x & 63;
    int l = lane & 15;                  // lane in group; covers elems [l*4, l*4+4)
    int gb = lane & 48;                 // group base lane within wave
    int l4 = l * 4;
    int grp = threadIdx.x >> 4;         // 0..15 = row in tile
    int v0 = blockIdx.x * 16;
    int v = v0 + grp;                   // (NU+NI) % 16 == 0; block phase-uniform
    int phase = v >= NU;
    int vtx = phase ? v - NU : v;
    const bf16_t* other = phase ? uh : ih;
    const void* pv = phase ? i_pos : u_pos;
    int j0 = off[v], j1 = off[v + 1];   // user segs [0,NU), item segs [NU,2NU)
    f32x4 a0 = (f32x4){0.f, 0.f, 0.f, 0.f}, a1 = a0;
    float s1 = 0.f, s2 = 0.f;
    for (int cb = j0; cb < j1; cb += 16) {
        int m = j1 - cb; if (m > 16) m = 16;
        uint2 pay = make_uint2(0u, 0u);
        if (l < m) pay = perm[cb + l];
        unsigned px0 = (unsigned)__shfl((int)pay.x, gb, 64);
        unsigned py0 = (unsigned)__shfl((int)pay.y, gb, 64);
        f32x4 ho0 = bf4(other + (size_t)(px0 & 0x1FFFF) * 64 + l4);
        f32x4 pv0 = ldf4(pv, (size_t)((px0 >> 17) & 63) * 64 + l4, f);
        for (int k = 0; k < m; ++k) {
            unsigned px1 = 0, py1 = 0;
            f32x4 ho1 = (f32x4){0.f, 0.f, 0.f, 0.f}, pv1 = ho1;
            if (k + 1 < m) {
                px1 = (unsigned)__shfl((int)pay.x, gb + k + 1, 64);
                py1 = (unsigned)__shfl((int)pay.y, gb + k + 1, 64);
                ho1 = bf4(other + (size_t)(px1 & 0x1FFFF) * 64 + l4);
                pv1 = ldf4(pv, (size_t)((px1 >> 17) & 63) * 64 + l4, f);
            }
            float p1 = __half2float(__ushort_as_half((unsigned short)(py0 & 0xFFFF)));
            float p2 = __half2float(__ushort_as_half((unsigned short)(py0 >> 16)));
#pragma unroll
            for (int q = 0; q < 4; ++q) {
                a0[q] = fmaf(p1, ho0[q] + pv0[q], a0[q]);
                a1[q] = fmaf(p2, ho0[q], a1[q]);
            }
            s1 += p1; s2 += p2;
            px0 = px1; py0 = py1; ho0 = ho1; pv0 = pv1;
        }
    }
    float inv1 = 1.f / (s1 + 1e-9f), inv2 = 1.f / (s2 + 1e-9f);
    {
        short4v o0, o1;
#pragma unroll
        for (int q = 0; q < 4; ++q) {
            o0[q] = (short)f2bu(a0[q] * inv1);
            o1[q] = (short)f2bu(a1[q] * inv2);
        }
        *(short4v*)&AG[grp * AGS + l4] = o0;
        *(short4v*)&AG[grp * AGS + 64 + l4] = o1;
    }
    if (phase) {
        f32x4 r0 = (f32x4){0.f, 0.f, 0.f, 0.f}, r1 = r0, r2 = r0;
        int c0 = 0, c1 = 0, c2 = 0;
        int k0 = off[2 * NU + vtx], k1 = off[2 * NU + vtx + 1];
        for (int cb = k0; cb < k1; cb += 16) {
            int m = k1 - cb; if (m > 16) m = 16;
            unsigned px = 0u;
            if (l < m) px = perm[cb + l].x;
            unsigned u0 = (unsigned)__shfl((int)px, gb, 64);
            f32x4 fv0 = bf4(fW + (size_t)(u0 & 0x1FFFF) * 64 + l4);
            for (int k = 0; k < m; ++k) {
                unsigned u1 = 0;
                f32x4 fv1 = (f32x4){0.f, 0.f, 0.f, 0.f};
                if (k + 1 < m) {
                    u1 = (unsigned)__shfl((int)px, gb + k + 1, 64);
                    fv1 = bf4(fW + (size_t)(u1 & 0x1FFFF) * 64 + l4);
                }
                int r = (u0 >> 17) & 3;
                if (r == 0) {
#pragma unroll
                    for (int q = 0; q < 4; ++q) r0[q] += fv0[q];
                    c0++;
                } else if (r == 1) {
#pragma unroll
                    for (int q = 0; q < 4; ++q) r1[q] += fv0[q];
                    c1++;
                } else {
#pragma unroll
                    for (int q = 0; q < 4; ++q) r2[q] += fv0[q];
                    c2++;
                }
                u0 = u1; fv0 = fv1;
            }
        }
        float w0 = 1.f / fmaxf((float)c0, 1.f);
        float w1 = 1.f / fmaxf((float)c1, 1.f);
        float w2 = 1.f / fmaxf((float)c2, 1.f);
        short4v ro;
#pragma unroll
        for (int q = 0; q < 4; ++q)
            ro[q] = (short)f2bu(r0[q] * w0 + r1[q] * w1 + r2[q] * w2);
        *(short4v*)&RL[grp * RLS + l4] = ro;
    }
    __syncthreads();
    // ---- MFMA: wave wv computes cols [wv*16, wv*16+16) of the 16x64 tile ----
    int wv = threadIdx.x >> 6;
    int q = lane >> 4, nl = lane & 15;
    const bf16_t* wg = wgsw + (phase ? 8192 : 0);
    f32x4 acc = (f32x4){0.f, 0.f, 0.f, 0.f};
#pragma unroll
    for (int kk = 0; kk < 4; ++kk) {
        short8 af = *(const short8*)&AG[nl * AGS + kk * 32 + q * 8];
        short8 bfr = *(const short8*)&wg[(((kk << 2) + wv) * 64 + lane) * 8];
        acc = __builtin_amdgcn_mfma_f32_16x16x32_bf16(af, bfr, acc, 0, 0, 0);
    }
    const void* hext = phase ? item_h : user_h;
    int hbase = phase ? v0 - NU : v0;
#pragma unroll
    for (int r = 0; r < 4; ++r) {
        int row = q * 4 + r;               // vertex within tile
        int col = wv * 16 + nl;
        float val = acc[r];
        val += ldf(hext, (size_t)(hbase + row) * 64 + col, f);
        if (phase) val += b2f(((const bf16_t*)RL)[row * RLS + col]);
        val = val > 0.f ? val : expm1f(val);
        stf(d_out, (size_t)(v0 + row) * 64 + col, sane(val), f);
    }
}

extern "C" void kernel_launch(void* const* d_in, const int* in_sizes, int n_in,
                              void* d_out, int out_size, void* d_ws, size_t ws_size,
                              hipStream_t stream) {
    const void* user_h     = d_in[0];
    const void* item_h     = d_in[1];
    const void* brand_feat = d_in[2];
    const void* cat_feat   = d_in[3];
    const void* rel_feat   = d_in[4];
    const void* Wu   = d_in[5];
    const void* Wi   = d_in[6];
    const void* Wb   = d_in[7];
    const void* Wc   = d_in[8];
    const void* Wr   = d_in[9];
    const void* Wg_u = d_in[10];
    const void* Wg_i = d_in[11];
    const void* u_pos   = d_in[12];
    const void* u_pos_k = d_in[13];
    const void* i_pos   = d_in[14];
    const void* i_pos_k = d_in[15];
    const void* basis_freq = d_in[16];
    const void* phase      = d_in[17];
    const void* Wr0 = d_in[18];
    const void* Wr1 = d_in[19];
    const void* Wr2 = d_in[20];
    const void* e_time = d_in[21];
    const int* e_iid  = (const int*)d_in[22];
    const int* e_uid  = (const int*)d_in[23];
    const int* pos_u  = (const int*)d_in[24];
    const int* pos_i  = (const int*)d_in[25];
    const int* eb_src = (const int*)d_in[26];
    const int* eb_dst = (const int*)d_in[27];
    const int* ec_src = (const int*)d_in[28];
    const int* ec_dst = (const int*)d_in[29];
    const int* er_src = (const int*)d_in[30];
    const int* er_dst = (const int*)d_in[31];

    char* base = (char*)d_ws;
    size_t off_b = 0;
    auto alloc = [&](size_t bytes) { size_t p = off_b; off_b = (off_b + bytes + 511) & ~(size_t)511; return p; };
    size_t o_flag  = alloc(512);
    size_t o_uh    = alloc((size_t)NU * 64 * 2);                 // 12.8 MB
    size_t o_ih    = alloc((size_t)NI * 64 * 2);                 // 12.8 MB
    size_t o_fW    = alloc((size_t)(NB_ + NC_ + NR_ + 64) * 64 * 2); // 7.3 MB
    size_t o_wcomb = alloc((size_t)3 * 4096 * 2);
    size_t o_wgsw  = alloc((size_t)2 * 8192 * 2);                // 32 KB
    size_t o_deg   = alloc((size_t)SCAN_N * 4);
    size_t o_off   = alloc((size_t)SCAN_N * 4);
    size_t o_cur   = alloc((size_t)SCAN_N * 4);
    size_t o_ctot  = alloc((size_t)SCAN_NCHUNK * 4);
    size_t o_perm  = alloc((size_t)NPERM * 8);                   // 15.2 MB

    int*    flagp = (int*)(base + o_flag);
    bf16_t* uh    = (bf16_t*)(base + o_uh);
    bf16_t* ih    = (bf16_t*)(base + o_ih);
    bf16_t* fW    = (bf16_t*)(base + o_fW);
    bf16_t* wcomb = (bf16_t*)(base + o_wcomb);
    bf16_t* wgsw  = (bf16_t*)(base + o_wgsw);
    int*    deg   = (int*)(base + o_deg);
    int*    offp  = (int*)(base + o_off);
    int*    cur   = (int*)(base + o_cur);
    int*    ctot  = (int*)(base + o_ctot);
    uint2*  perm  = (uint2*)(base + o_perm);

    hipMemsetAsync(deg, 0, (size_t)SCAN_N * 4, stream);
    detect_dtype<<<1, 64, 0, stream>>>((const unsigned int*)basis_freq, flagp);

    combine_w<<<112, 256, 0, stream>>>(Wb, Wr0, Wc, Wr1, Wr, Wr2, Wg_u, Wg_i,
                                       wcomb, wgsw, flagp);

    // all K=64 GEMMs + degree histogram in ONE launch
    {
        GSeg su = {user_h,     Wu,           uh,                            NU,  0, 0};
        GSeg si = {item_h,     Wi,           ih,                            NI,  0, 0};
        GSeg sb = {brand_feat, wcomb,        fW,                            NB_, 0, 1};
        GSeg sc = {cat_feat,   wcomb + 4096, fW + (size_t)NB_ * 64,         NC_, 0, 1};
        GSeg sr = {rel_feat,   wcomb + 8192, fW + (size_t)(NB_ + NC_) * 64, NR_, 0, 1};
        gemm_hist<<<GEMM_BLKS + HIST_BLKS, 256, 0, stream>>>(
            su, si, sb, sc, sr, 5, flagp,
            e_uid, e_iid, eb_dst, ec_dst, er_dst, deg);
    }

    scan1<<<SCAN_NCHUNK, 256, 0, stream>>>(deg, offp, ctot);
    scan23<<<SCAN_NCHUNK, 256, 0, stream>>>(offp, ctot, cur);

    edges_fused<<<PBLK + RBLK, 256, 0, stream>>>(uh, ih, u_pos_k, i_pos_k, basis_freq, phase,
                                                 e_time, e_uid, e_iid, pos_u, pos_i,
                                                 eb_src, eb_dst, ec_src, ec_dst,
                                                 er_src, er_dst, cur, perm, flagp);

    // gather + final GEMM + residual + elu, single launch
    gather_gemm<<<(NU + NI) / 16, 256, 0, stream>>>(uh, ih, u_pos, i_pos, offp, perm, fW,
                                                    wgsw, user_h, item_h, d_out, flagp);
}

// Round 12
// 497.311 us; speedup vs baseline: 1.4942x; 1.0030x over previous
//
#include <hip/hip_runtime.h>
#include <hip/hip_bf16.h>
#include <hip/hip_fp16.h>

typedef __hip_bfloat16 bf16_t;

#define NU 100000
#define NI 100000
#define NB_ 5000
#define NC_ 2000
#define NR_ 50000
#define NE 600000
#define NEB 100000
#define NEC 200000
#define NER 400000
#define NPERM (2 * NE + NEB + NEC + NER)   // 1,900,000
#define NRELE (NEB + NEC + NER)            // 700,000
#define NALL (NE + NRELE)
#define SCAN_N (2 * NU + NI + 1)
#define SCAN_CHUNK 2048
#define SCAN_NCHUNK ((SCAN_N + SCAN_CHUNK - 1) / SCAN_CHUNK)   // 147
#define PBLK 4096                          // purchase blocks in fused edge kernel
#define RBLK ((NRELE + 255) / 256)         // rel-scatter blocks
#define GEMM_BLKS 1024                     // gemm blocks in merged gemm+hist launch
#define HIST_BLKS 2048

// LDS row strides (shorts) chosen for 16B alignment + conflict-freedom
#define AGS 136
#define RLS 68

typedef __attribute__((ext_vector_type(8))) short short8;
typedef __attribute__((ext_vector_type(4))) short short4v;
typedef __attribute__((ext_vector_type(4))) float f32x4;

__device__ __forceinline__ float b2f(bf16_t x) { return __bfloat162float(x); }
__device__ __forceinline__ float sane(float x) { return isfinite(x) ? x : 0.f; }
__device__ __forceinline__ unsigned short f2bu(float x) {
    union { bf16_t b; unsigned short u; } c; c.b = __float2bfloat16(x); return c.u;
}

// dual-dtype load/store: external float tensors are f32 or bf16, per runtime flag
__device__ __forceinline__ float ldf(const void* p, size_t i, int f32) {
    return f32 ? ((const float*)p)[i] : __bfloat162float(((const bf16_t*)p)[i]);
}
__device__ __forceinline__ void stf(void* p, size_t i, float v, int f32) {
    if (f32) ((float*)p)[i] = v;
    else     ((bf16_t*)p)[i] = __float2bfloat16(v);
}

// 4-wide packed loads (i must be a multiple of 4 elements)
__device__ __forceinline__ f32x4 bf4(const bf16_t* p) {
    short4v s = *(const short4v*)p;
    f32x4 r;
#pragma unroll
    for (int q = 0; q < 4; ++q)
        r[q] = __uint_as_float(((unsigned)(unsigned short)s[q]) << 16);
    return r;
}
__device__ __forceinline__ f32x4 ldf4(const void* p, size_t i, int f32) {
    if (f32) return *(const f32x4*)((const float*)p + i);
    return bf4((const bf16_t*)p + i);
}

// 8-wide packed loads (i must be a multiple of 8 elements)
__device__ __forceinline__ void bf8(const bf16_t* p, float* o) {
    short8 s = *(const short8*)p;
#pragma unroll
    for (int q = 0; q < 8; ++q)
        o[q] = __uint_as_float(((unsigned)(unsigned short)s[q]) << 16);
}
__device__ __forceinline__ void ldf8(const void* p, size_t i, int f32, float* o) {
    if (f32) {
        f32x4 a = *(const f32x4*)((const float*)p + i);
        f32x4 b = *(const f32x4*)((const float*)p + i + 4);
#pragma unroll
        for (int q = 0; q < 4; ++q) { o[q] = a[q]; o[4 + q] = b[q]; }
    } else {
        bf8((const bf16_t*)p + i, o);
    }
}

// ---- dtype probe: basis_freq[0] == 1.0f exactly; f32 word = 0x3F800000 ----
__global__ void detect_dtype(const unsigned int* w, int* flag) {
    if (threadIdx.x == 0 && blockIdx.x == 0) *flag = (w[0] == 0x3F800000u) ? 1 : 0;
}

// ---- blocks 0..47: wcomb_r = W_feat_r @ Wr_r (bf16, 1 out/thread)
// ---- blocks 48..111: pre-swizzle Wg_u/Wg_i into MFMA B-frag layout ----
__global__ __launch_bounds__(256) void combine_w(
    const void* Wb, const void* Wr0,
    const void* Wc, const void* Wr1,
    const void* Wr, const void* Wr2,
    const void* Wg_u, const void* Wg_i,
    bf16_t* out, bf16_t* wgsw, const int* flagp) {
    int f = *flagp;
    if (blockIdx.x < 48) {
        int mat = blockIdx.x >> 4;          // 0..2
        int sub = blockIdx.x & 15;          // 0..15
        const void* A = mat == 0 ? Wb : (mat == 1 ? Wc : Wr);
        const void* B = mat == 0 ? Wr0 : (mat == 1 ? Wr1 : Wr2);
        int idx = sub * 256 + threadIdx.x;  // 0..4095
        int i = idx >> 6, j = idx & 63;
        float acc = 0.f;
        for (int k = 0; k < 64; ++k)
            acc = fmaf(ldf(A, i * 64 + k, f), ldf(B, k * 64 + j, f), acc);
        out[(size_t)mat * 4096 + idx] = __float2bfloat16(acc);
    } else {
        // swizzle: wgsw[mat*8192 + ((kk4*4+n0t)*64+ln)*8+j] = Wg[srow][scol]
        int t = (blockIdx.x - 48) * 256 + threadIdx.x;   // 0..16383
        int mat = t >> 13;                  // 0: Wg_u, 1: Wg_i
        int i = t & 8191;
        int j = i & 7, ln = (i >> 3) & 63, p = i >> 9;   // p 0..15
        int kk4 = p >> 2, n0t = p & 3;
        int srow = kk4 * 32 + (ln >> 4) * 8 + j;         // 0..127
        int scol = n0t * 16 + (ln & 15);
        const void* src = mat ? Wg_i : Wg_u;
        wgsw[(size_t)mat * 8192 + i] = __float2bfloat16(ldf(src, (size_t)srow * 64 + scol, f));
    }
}

// ============================================================================
// Merged launch: blocks [0,GEMM_BLKS) run the segmented K=64 MFMA GEMM
// (up to 5 segments, W staged in LDS per segment); blocks >= GEMM_BLKS run
// the degree histogram grid-strided. Independent work, co-scheduled so the
// histogram's atomic latency hides under MFMA waves.
// ============================================================================
struct GSeg {
    const void* A; const void* W; void* out;
    int M; int a_internal; int w_internal;
};

__global__ __launch_bounds__(256) void gemm_hist(
    GSeg s0, GSeg s1, GSeg s2, GSeg s3, GSeg s4,
    int nseg, const int* __restrict__ flagp,
    const int* __restrict__ e_uid, const int* __restrict__ e_iid,
    const int* __restrict__ eb_dst, const int* __restrict__ ec_dst,
    const int* __restrict__ er_dst, int* __restrict__ deg) {
    if (blockIdx.x >= GEMM_BLKS) {
        int tid = (blockIdx.x - GEMM_BLKS) * 256 + threadIdx.x;
        const int nthr = HIST_BLKS * 256;
        for (int t = tid; t < NALL; t += nthr) {
            if (t < NE) {
                atomicAdd(deg + e_uid[t], 1);
                atomicAdd(deg + NU + e_iid[t], 1);
            } else if (t < NE + NEB) {
                atomicAdd(deg + 2 * NU + eb_dst[t - NE], 1);
            } else if (t < NE + NEB + NEC) {
                atomicAdd(deg + 2 * NU + ec_dst[t - NE - NEB], 1);
            } else {
                atomicAdd(deg + 2 * NU + er_dst[t - NE - NEB - NEC], 1);
            }
        }
        return;
    }
    const int K = 64;
    __shared__ short WL[64 * 64];
    int f = *flagp;
    int nt0 = (s0.M + 63) >> 6;
    int nt1 = (nseg > 1) ? ((s1.M + 63) >> 6) : 0;
    int nt2 = (nseg > 2) ? ((s2.M + 63) >> 6) : 0;
    int nt3 = (nseg > 3) ? ((s3.M + 63) >> 6) : 0;
    int nt4 = (nseg > 4) ? ((s4.M + 63) >> 6) : 0;
    int c0 = nt0, c1 = c0 + nt1, c2 = c1 + nt2, c3 = c2 + nt3;
    int ntT = c3 + nt4;
    int lane = threadIdx.x & 63;
    int wv = threadIdx.x >> 6;
    int q = lane >> 4, nl = lane & 15;
    int staged = -1;
    for (int tile = blockIdx.x; tile < ntT; tile += GEMM_BLKS) {
        int sidx, t_in;
        if (tile < c0) { sidx = 0; t_in = tile; }
        else if (tile < c1) { sidx = 1; t_in = tile - c0; }
        else if (tile < c2) { sidx = 2; t_in = tile - c1; }
        else if (tile < c3) { sidx = 3; t_in = tile - c2; }
        else { sidx = 4; t_in = tile - c3; }
        const void* A; const void* W; void* out; int M, a_int, w_int;
        if (sidx == 0)      { A = s0.A; W = s0.W; out = s0.out; M = s0.M; a_int = s0.a_internal; w_int = s0.w_internal; }
        else if (sidx == 1) { A = s1.A; W = s1.W; out = s1.out; M = s1.M; a_int = s1.a_internal; w_int = s1.w_internal; }
        else if (sidx == 2) { A = s2.A; W = s2.W; out = s2.out; M = s2.M; a_int = s2.a_internal; w_int = s2.w_internal; }
        else if (sidx == 3) { A = s3.A; W = s3.W; out = s3.out; M = s3.M; a_int = s3.a_internal; w_int = s3.w_internal; }
        else                { A = s4.A; W = s4.W; out = s4.out; M = s4.M; a_int = s4.a_internal; w_int = s4.w_internal; }
        if (sidx != staged) {                       // block-uniform condition
            __syncthreads();                        // drain readers of old WL
            int w_f32 = w_int ? 0 : f;
            for (int i = threadIdx.x; i < K * 64; i += 256) {
                int j = i & 7, ln = (i >> 3) & 63, p = i >> 9;
                int kk4 = p >> 2, n0t = p & 3;
                int srow = kk4 * 32 + (ln >> 4) * 8 + j;
                int scol = n0t * 16 + (ln & 15);
                float wvv = w_f32 ? ((const float*)W)[srow * 64 + scol]
                                  : b2f(((const bf16_t*)W)[srow * 64 + scol]);
                WL[i] = (short)f2bu(wvv);
            }
            __syncthreads();
            staged = sidx;
        }
        int m0 = t_in * 64 + wv * 16;
        if (m0 < M) {
            int a_f32 = a_int ? 0 : f;
            int arow = m0 + nl; if (arow >= M) arow = M - 1;
            f32x4 acc[4];
#pragma unroll
            for (int t = 0; t < 4; ++t) acc[t] = (f32x4){0.f, 0.f, 0.f, 0.f};
            for (int kk4 = 0; kk4 < 2; ++kk4) {
                short8 af;
                size_t abase = (size_t)arow * K + kk4 * 32 + q * 8;
                if (a_f32) {
                    const f32x4* ap = (const f32x4*)((const float*)A + abase);
                    f32x4 x0 = ap[0], x1 = ap[1];
#pragma unroll
                    for (int j = 0; j < 4; ++j) {
                        af[j] = (short)f2bu(x0[j]);
                        af[4 + j] = (short)f2bu(x1[j]);
                    }
                } else {
                    af = *(const short8*)((const bf16_t*)A + abase);
                }
#pragma unroll
                for (int n0t = 0; n0t < 4; ++n0t) {
                    short8 bfr = *(const short8*)&WL[(((kk4 << 2) + n0t) * 64 + lane) * 8];
                    acc[n0t] = __builtin_amdgcn_mfma_f32_16x16x32_bf16(af, bfr, acc[n0t], 0, 0, 0);
                }
            }
#pragma unroll
            for (int n0t = 0; n0t < 4; ++n0t) {
#pragma unroll
                for (int r = 0; r < 4; ++r) {
                    int row = m0 + q * 4 + r;
                    if (row >= M) continue;
                    int col = n0t * 16 + nl;
                    ((bf16_t*)out)[(size_t)row * 64 + col] = __float2bfloat16(acc[n0t][r]);
                }
            }
        }
    }
}

// ---- exclusive scan over SCAN_N ints ----
__global__ __launch_bounds__(256) void scan1(const int* __restrict__ deg,
                                             int* __restrict__ off,
                                             int* __restrict__ ctot) {
    __shared__ int part[256];
    int base = blockIdx.x * SCAN_CHUNK + threadIdx.x * 8;
    int v[8]; int s = 0;
#pragma unroll
    for (int k = 0; k < 8; ++k) {
        int idx = base + k;
        v[k] = s;
        s += (idx < SCAN_N) ? deg[idx] : 0;
    }
    part[threadIdx.x] = s;
    __syncthreads();
    for (int o = 1; o < 256; o <<= 1) {
        int t = (threadIdx.x >= o) ? part[threadIdx.x - o] : 0;
        __syncthreads();
        part[threadIdx.x] += t;
        __syncthreads();
    }
    int texc = (threadIdx.x == 0) ? 0 : part[threadIdx.x - 1];
#pragma unroll
    for (int k = 0; k < 8; ++k) {
        int idx = base + k;
        if (idx < SCAN_N) off[idx] = texc + v[k];
    }
    if (threadIdx.x == 255) ctot[blockIdx.x] = part[255];
}
// merged scan2+scan3: every block redundantly scans ctot (147 ints) in LDS,
// picks its own chunk offset, applies it, and initializes cur.
__global__ __launch_bounds__(256) void scan23(int* __restrict__ off,
                                              const int* __restrict__ ctot,
                                              int* __restrict__ cur) {
    __shared__ int part[256];
    int t = threadIdx.x;
    part[t] = (t < SCAN_NCHUNK) ? ctot[t] : 0;
    __syncthreads();
    for (int o = 1; o < 256; o <<= 1) {
        int x = (t >= o) ? part[t - o] : 0;
        __syncthreads();
        part[t] += x;
        __syncthreads();
    }
    int add = blockIdx.x ? part[blockIdx.x - 1] : 0;
    int base = blockIdx.x * SCAN_CHUNK + t;
#pragma unroll
    for (int k = 0; k < 8; ++k) {
        int idx = base + k * 256;
        if (idx < SCAN_N) { int v = off[idx] + add; off[idx] = v; cur[idx] = v; }
    }
}

// ---- fused edge kernel: purchase (8 edges/wave, 8 lanes each) + rel scatter ----
// payload: {nbr | pos<<17,  f16(p_long) | f16(p_short)<<16}
// Lane 0 issues BOTH slot atomics at the TOP of the iteration (they depend
// only on uid/iid); their round trips hide under the row loads + cos/fma +
// butterfly. Both payload stores consume the slots at the end (single-lane
// structure = R7's proven register footprint).
__global__ __launch_bounds__(256) void edges_fused(
    const bf16_t* __restrict__ uh, const bf16_t* __restrict__ ih,
    const void* __restrict__ u_pos_k, const void* __restrict__ i_pos_k,
    const void* __restrict__ basis_freq, const void* __restrict__ phase_,
    const void* __restrict__ e_time,
    const int* __restrict__ e_uid, const int* __restrict__ e_iid,
    const int* __restrict__ pos_u, const int* __restrict__ pos_i,
    const int* __restrict__ eb_src, const int* __restrict__ eb_dst,
    const int* __restrict__ ec_src, const int* __restrict__ ec_dst,
    const int* __restrict__ er_src, const int* __restrict__ er_dst,
    int* __restrict__ cur, uint2* __restrict__ perm, const int* flagp) {
    if (blockIdx.x >= PBLK) {
        // relation edge payload scatter, thread per edge
        int t = (blockIdx.x - PBLK) * 256 + threadIdx.x;
        if (t < NEB) {
            int p = atomicAdd(cur + 2 * NU + eb_dst[t], 1);
            perm[p] = make_uint2((unsigned)eb_src[t], 0u);
        } else if (t < NEB + NEC) {
            int e = t - NEB;
            int p = atomicAdd(cur + 2 * NU + ec_dst[e], 1);
            perm[p] = make_uint2((unsigned)(ec_src[e] + NB_) | (1u << 17), 0u);
        } else if (t < NRELE) {
            int e = t - NEB - NEC;
            int p = atomicAdd(cur + 2 * NU + er_dst[e], 1);
            perm[p] = make_uint2((unsigned)(er_src[e] + NB_ + NC_) | (2u << 17), 0u);
        }
        return;
    }
    int f = *flagp;
    int lane = threadIdx.x & 63;
    int g = lane >> 3, l = lane & 7;   // 8 groups x 8 lanes; lane covers 8 elems (16B loads)
    float bfv[8], phv[8];
    ldf8(basis_freq, (size_t)l * 8, f, bfv);
    ldf8(phase_, (size_t)l * 8, f, phv);
    int w = (blockIdx.x * 256 + threadIdx.x) >> 6;
    const int NWAVE = PBLK * 4;
    for (int eb = w; eb < NE / 8; eb += NWAVE) {
        int e = eb * 8 + g;                 // NE % 8 == 0, always in range
        int uid = e_uid[e], iid = e_iid[e], pu = pos_u[e], pi = pos_i[e];
        // ---- issue both slot atomics early; independent of the math below ----
        int s1 = 0, s2 = 0;
        if (l == 0) {
            s1 = atomicAdd(cur + uid, 1);
            s2 = atomicAdd(cur + NU + iid, 1);
        }
        float t = ldf(e_time, e, f);
        float hu[8], hi[8], pku[8], pki[8];
        bf8(uh + (size_t)uid * 64 + l * 8, hu);
        bf8(ih + (size_t)iid * 64 + l * 8, hi);
        ldf8(u_pos_k, (size_t)pu * 64 + l * 8, f, pku);
        ldf8(i_pos_k, (size_t)pi * 64 + l * 8, f, pki);
        float d_lu = 0.f, d_sh = 0.f, d_li = 0.f;
#pragma unroll
        for (int qq = 0; qq < 8; ++qq) {
            float te = __cosf(fmaf(t, bfv[qq], phv[qq]));
            d_lu = fmaf(hi[qq] + pku[qq] + te, hu[qq], d_lu);
            d_sh = fmaf(hi[qq], hu[qq], d_sh);
            d_li = fmaf(hu[qq] + pki[qq] + te, hi[qq], d_li);
        }
#pragma unroll
        for (int o = 1; o < 8; o <<= 1) {
            d_lu += __shfl_xor(d_lu, o, 64);
            d_sh += __shfl_xor(d_sh, o, 64);
            d_li += __shfl_xor(d_li, o, 64);
        }
        if (l == 0) {
            float p_lu = __expf(fminf(d_lu * 0.125f, 10.f));   // clamp protects f16 pack
            float p_sh = __expf(fminf(d_sh * 0.125f, 10.f));
            float p_li = __expf(fminf(d_li * 0.125f, 10.f));
            unsigned pkt_u = (unsigned)__half_as_ushort(__float2half(p_lu))
                           | ((unsigned)__half_as_ushort(__float2half(p_sh)) << 16);
            unsigned pkt_i = (unsigned)__half_as_ushort(__float2half(p_li))
                           | ((unsigned)__half_as_ushort(__float2half(p_sh)) << 16);
            perm[s1] = make_uint2((unsigned)iid | ((unsigned)pu << 17), pkt_u);
            perm[s2] = make_uint2((unsigned)uid | ((unsigned)pi << 17), pkt_i);
        }
    }
}

// ============================================================================
// Fused gather + final GEMM + residual + elu.
// Block = 16 consecutive vertices (one per 16-lane group). Gather with
// 2-deep pipelined neighbor loop (R9's proven structure); agg rows (and
// relv) deposited in LDS; one barrier; then each wave computes the 16x16
// output slice via 4 MFMAs with pre-swizzled Wg B-fragments read from
// global (L2-hot). Epilogue adds hext (+relb), elu, stores to d_out.
// ============================================================================
__global__ __launch_bounds__(256) void gather_gemm(
    const bf16_t* __restrict__ uh, const bf16_t* __restrict__ ih,
    const void* __restrict__ u_pos, const void* __restrict__ i_pos,
    const int* __restrict__ off, const uint2* __restrict__ perm,
    const bf16_t* __restrict__ fW, const bf16_t* __restrict__ wgsw,
    const void* __restrict__ user_h, const void* __restrict__ item_h,
    void* __restrict__ d_out, const int* flagp) {
    __shared__ short AG[16 * AGS];       // agg tile [16][128], stride 136
    __shared__ short RL[16 * RLS];       // relv tile [16][64], stride 68
    int f = *flagp;
    int lane = threadIdx.x & 63;
    int l = lane & 15;                  // lane in group; covers elems [l*4, l*4+4)
    int gb = lane & 48;                 // group base lane within wave
    int l4 = l * 4;
    int grp = threadIdx.x >> 4;         // 0..15 = row in tile
    int v0 = blockIdx.x * 16;
    int v = v0 + grp;                   // (NU+NI) % 16 == 0; block phase-uniform
    int phase = v >= NU;
    int vtx = phase ? v - NU : v;
    const bf16_t* other = phase ? uh : ih;
    const void* pv = phase ? i_pos : u_pos;
    int j0 = off[v], j1 = off[v + 1];   // user segs [0,NU), item segs [NU,2NU)
    f32x4 a0 = (f32x4){0.f, 0.f, 0.f, 0.f}, a1 = a0;
    float s1 = 0.f, s2 = 0.f;
    for (int cb = j0; cb < j1; cb += 16) {
        int m = j1 - cb; if (m > 16) m = 16;
        uint2 pay = make_uint2(0u, 0u);
        if (l < m) pay = perm[cb + l];
        unsigned px0 = (unsigned)__shfl((int)pay.x, gb, 64);
        unsigned py0 = (unsigned)__shfl((int)pay.y, gb, 64);
        f32x4 ho0 = bf4(other + (size_t)(px0 & 0x1FFFF) * 64 + l4);
        f32x4 pv0 = ldf4(pv, (size_t)((px0 >> 17) & 63) * 64 + l4, f);
        for (int k = 0; k < m; ++k) {
            unsigned px1 = 0, py1 = 0;
            f32x4 ho1 = (f32x4){0.f, 0.f, 0.f, 0.f}, pv1 = ho1;
            if (k + 1 < m) {
                px1 = (unsigned)__shfl((int)pay.x, gb + k + 1, 64);
                py1 = (unsigned)__shfl((int)pay.y, gb + k + 1, 64);
                ho1 = bf4(other + (size_t)(px1 & 0x1FFFF) * 64 + l4);
                pv1 = ldf4(pv, (size_t)((px1 >> 17) & 63) * 64 + l4, f);
            }
            float p1 = __half2float(__ushort_as_half((unsigned short)(py0 & 0xFFFF)));
            float p2 = __half2float(__ushort_as_half((unsigned short)(py0 >> 16)));
#pragma unroll
            for (int q = 0; q < 4; ++q) {
                a0[q] = fmaf(p1, ho0[q] + pv0[q], a0[q]);
                a1[q] = fmaf(p2, ho0[q], a1[q]);
            }
            s1 += p1; s2 += p2;
            px0 = px1; py0 = py1; ho0 = ho1; pv0 = pv1;
        }
    }
    float inv1 = 1.f / (s1 + 1e-9f), inv2 = 1.f / (s2 + 1e-9f);
    {
        short4v o0, o1;
#pragma unroll
        for (int q = 0; q < 4; ++q) {
            o0[q] = (short)f2bu(a0[q] * inv1);
            o1[q] = (short)f2bu(a1[q] * inv2);
        }
        *(short4v*)&AG[grp * AGS + l4] = o0;
        *(short4v*)&AG[grp * AGS + 64 + l4] = o1;
    }
    if (phase) {
        f32x4 r0 = (f32x4){0.f, 0.f, 0.f, 0.f}, r1 = r0, r2 = r0;
        int c0 = 0, c1 = 0, c2 = 0;
        int k0 = off[2 * NU + vtx], k1 = off[2 * NU + vtx + 1];
        for (int cb = k0; cb < k1; cb += 16) {
            int m = k1 - cb; if (m > 16) m = 16;
            unsigned px = 0u;
            if (l < m) px = perm[cb + l].x;
            unsigned u0 = (unsigned)__shfl((int)px, gb, 64);
            f32x4 fv0 = bf4(fW + (size_t)(u0 & 0x1FFFF) * 64 + l4);
            for (int k = 0; k < m; ++k) {
                unsigned u1 = 0;
                f32x4 fv1 = (f32x4){0.f, 0.f, 0.f, 0.f};
                if (k + 1 < m) {
                    u1 = (unsigned)__shfl((int)px, gb + k + 1, 64);
                    fv1 = bf4(fW + (size_t)(u1 & 0x1FFFF) * 64 + l4);
                }
                int r = (u0 >> 17) & 3;
                if (r == 0) {
#pragma unroll
                    for (int q = 0; q < 4; ++q) r0[q] += fv0[q];
                    c0++;
                } else if (r == 1) {
#pragma unroll
                    for (int q = 0; q < 4; ++q) r1[q] += fv0[q];
                    c1++;
                } else {
#pragma unroll
                    for (int q = 0; q < 4; ++q) r2[q] += fv0[q];
                    c2++;
                }
                u0 = u1; fv0 = fv1;
            }
        }
        float w0 = 1.f / fmaxf((float)c0, 1.f);
        float w1 = 1.f / fmaxf((float)c1, 1.f);
        float w2 = 1.f / fmaxf((float)c2, 1.f);
        short4v ro;
#pragma unroll
        for (int q = 0; q < 4; ++q)
            ro[q] = (short)f2bu(r0[q] * w0 + r1[q] * w1 + r2[q] * w2);
        *(short4v*)&RL[grp * RLS + l4] = ro;
    }
    __syncthreads();
    // ---- MFMA: wave wv computes cols [wv*16, wv*16+16) of the 16x64 tile ----
    int wv = threadIdx.x >> 6;
    int q = lane >> 4, nl = lane & 15;
    const bf16_t* wg = wgsw + (phase ? 8192 : 0);
    f32x4 acc = (f32x4){0.f, 0.f, 0.f, 0.f};
#pragma unroll
    for (int kk = 0; kk < 4; ++kk) {
        short8 af = *(const short8*)&AG[nl * AGS + kk * 32 + q * 8];
        short8 bfr = *(const short8*)&wg[(((kk << 2) + wv) * 64 + lane) * 8];
        acc = __builtin_amdgcn_mfma_f32_16x16x32_bf16(af, bfr, acc, 0, 0, 0);
    }
    const void* hext = phase ? item_h : user_h;
    int hbase = phase ? v0 - NU : v0;
#pragma unroll
    for (int r = 0; r < 4; ++r) {
        int row = q * 4 + r;               // vertex within tile
        int col = wv * 16 + nl;
        float val = acc[r];
        val += ldf(hext, (size_t)(hbase + row) * 64 + col, f);
        if (phase) val += b2f(((const bf16_t*)RL)[row * RLS + col]);
        val = val > 0.f ? val : expm1f(val);
        stf(d_out, (size_t)(v0 + row) * 64 + col, sane(val), f);
    }
}

extern "C" void kernel_launch(void* const* d_in, const int* in_sizes, int n_in,
                              void* d_out, int out_size, void* d_ws, size_t ws_size,
                              hipStream_t stream) {
    const void* user_h     = d_in[0];
    const void* item_h     = d_in[1];
    const void* brand_feat = d_in[2];
    const void* cat_feat   = d_in[3];
    const void* rel_feat   = d_in[4];
    const void* Wu   = d_in[5];
    const void* Wi   = d_in[6];
    const void* Wb   = d_in[7];
    const void* Wc   = d_in[8];
    const void* Wr   = d_in[9];
    const void* Wg_u = d_in[10];
    const void* Wg_i = d_in[11];
    const void* u_pos   = d_in[12];
    const void* u_pos_k = d_in[13];
    const void* i_pos   = d_in[14];
    const void* i_pos_k = d_in[15];
    const void* basis_freq = d_in[16];
    const void* phase      = d_in[17];
    const void* Wr0 = d_in[18];
    const void* Wr1 = d_in[19];
    const void* Wr2 = d_in[20];
    const void* e_time = d_in[21];
    const int* e_iid  = (const int*)d_in[22];
    const int* e_uid  = (const int*)d_in[23];
    const int* pos_u  = (const int*)d_in[24];
    const int* pos_i  = (const int*)d_in[25];
    const int* eb_src = (const int*)d_in[26];
    const int* eb_dst = (const int*)d_in[27];
    const int* ec_src = (const int*)d_in[28];
    const int* ec_dst = (const int*)d_in[29];
    const int* er_src = (const int*)d_in[30];
    const int* er_dst = (const int*)d_in[31];

    char* base = (char*)d_ws;
    size_t off_b = 0;
    auto alloc = [&](size_t bytes) { size_t p = off_b; off_b = (off_b + bytes + 511) & ~(size_t)511; return p; };
    size_t o_flag  = alloc(512);
    size_t o_uh    = alloc((size_t)NU * 64 * 2);                 // 12.8 MB
    size_t o_ih    = alloc((size_t)NI * 64 * 2);                 // 12.8 MB
    size_t o_fW    = alloc((size_t)(NB_ + NC_ + NR_ + 64) * 64 * 2); // 7.3 MB
    size_t o_wcomb = alloc((size_t)3 * 4096 * 2);
    size_t o_wgsw  = alloc((size_t)2 * 8192 * 2);                // 32 KB
    size_t o_deg   = alloc((size_t)SCAN_N * 4);
    size_t o_off   = alloc((size_t)SCAN_N * 4);
    size_t o_cur   = alloc((size_t)SCAN_N * 4);
    size_t o_ctot  = alloc((size_t)SCAN_NCHUNK * 4);
    size_t o_perm  = alloc((size_t)NPERM * 8);                   // 15.2 MB

    int*    flagp = (int*)(base + o_flag);
    bf16_t* uh    = (bf16_t*)(base + o_uh);
    bf16_t* ih    = (bf16_t*)(base + o_ih);
    bf16_t* fW    = (bf16_t*)(base + o_fW);
    bf16_t* wcomb = (bf16_t*)(base + o_wcomb);
    bf16_t* wgsw  = (bf16_t*)(base + o_wgsw);
    int*    deg   = (int*)(base + o_deg);
    int*    offp  = (int*)(base + o_off);
    int*    cur   = (int*)(base + o_cur);
    int*    ctot  = (int*)(base + o_ctot);
    uint2*  perm  = (uint2*)(base + o_perm);

    hipMemsetAsync(deg, 0, (size_t)SCAN_N * 4, stream);
    detect_dtype<<<1, 64, 0, stream>>>((const unsigned int*)basis_freq, flagp);

    combine_w<<<112, 256, 0, stream>>>(Wb, Wr0, Wc, Wr1, Wr, Wr2, Wg_u, Wg_i,
                                       wcomb, wgsw, flagp);

    // all K=64 GEMMs + degree histogram in ONE launch
    {
        GSeg su = {user_h,     Wu,           uh,                            NU,  0, 0};
        GSeg si = {item_h,     Wi,           ih,                            NI,  0, 0};
        GSeg sb = {brand_feat, wcomb,        fW,                            NB_, 0, 1};
        GSeg sc = {cat_feat,   wcomb + 4096, fW + (size_t)NB_ * 64,         NC_, 0, 1};
        GSeg sr = {rel_feat,   wcomb + 8192, fW + (size_t)(NB_ + NC_) * 64, NR_, 0, 1};
        gemm_hist<<<GEMM_BLKS + HIST_BLKS, 256, 0, stream>>>(
            su, si, sb, sc, sr, 5, flagp,
            e_uid, e_iid, eb_dst, ec_dst, er_dst, deg);
    }

    scan1<<<SCAN_NCHUNK, 256, 0, stream>>>(deg, offp, ctot);
    scan23<<<SCAN_NCHUNK, 256, 0, stream>>>(offp, ctot, cur);

    edges_fused<<<PBLK + RBLK, 256, 0, stream>>>(uh, ih, u_pos_k, i_pos_k, basis_freq, phase,
                                                 e_time, e_uid, e_iid, pos_u, pos_i,
                                                 eb_src, eb_dst, ec_src, ec_dst,
                                                 er_src, er_dst, cur, perm, flagp);

    // gather + final GEMM + residual + elu, single launch
    gather_gemm<<<(NU + NI) / 16, 256, 0, stream>>>(uh, ih, u_pos, i_pos, offp, perm, fW,
                                                    wgsw, user_h, item_h, d_out, flagp);
}